// Round 1
// baseline (2982.582 us; speedup 1.0000x reference)
//
#include <hip/hip_runtime.h>

#define N_NODES 100000
#define N_EDGES 1600000

// ---------------- degree count ----------------
__global__ __launch_bounds__(256) void degree_kernel(const int* __restrict__ dst,
                                                     int* __restrict__ cnt) {
    int e = blockIdx.x * blockDim.x + threadIdx.x;
    if (e < N_EDGES) atomicAdd(&cnt[dst[e]], 1);
}

// ---------------- scatter-add of D-dim features (D = 1<<LOGD) ----------------
template <int LOGD>
__global__ __launch_bounds__(256) void scatter_kernel(const int* __restrict__ src,
                                                      const int* __restrict__ dst,
                                                      const float* __restrict__ feat,
                                                      float* __restrict__ agg) {
    const int D = 1 << LOGD;
    int tid = blockIdx.x * blockDim.x + threadIdx.x;
    if (tid >= N_EDGES * D) return;
    int e = tid >> LOGD;
    int f = tid & (D - 1);
    int s = src[e], d = dst[e];
    unsafeAtomicAdd(&agg[d * D + f], feat[s * D + f]);
}

// ---------------- SAGE layer 1: h1 = relu(mean@w1l^T + b1l + x@w1r^T) ----------------
// block = 128 threads = one node, one output feature per thread
__global__ __launch_bounds__(128) void layer1_kernel(const float* __restrict__ x,
                                                     const float* __restrict__ agg,
                                                     const int* __restrict__ cnt,
                                                     const float* __restrict__ w1l,
                                                     const float* __restrict__ b1l,
                                                     const float* __restrict__ w1r,
                                                     float* __restrict__ h1) {
    int i = blockIdx.x;
    int t = threadIdx.x;
    __shared__ float xs[64], ms[64];
    float inv = 1.0f / fmaxf((float)cnt[i], 1.0f);
    if (t < 64) xs[t] = x[i * 64 + t];
    else        ms[t - 64] = agg[i * 64 + (t - 64)] * inv;
    __syncthreads();
    int o = t;
    float acc = b1l[o];
    const float4* wl = (const float4*)(w1l + o * 64);
    const float4* wr = (const float4*)(w1r + o * 64);
    const float4* msv = (const float4*)ms;
    const float4* xsv = (const float4*)xs;
#pragma unroll
    for (int k = 0; k < 16; ++k) {
        float4 a = wl[k], b = wr[k];
        float4 m = msv[k], xv = xsv[k];
        acc += m.x * a.x + m.y * a.y + m.z * a.z + m.w * a.w;
        acc += xv.x * b.x + xv.y * b.y + xv.z * b.z + xv.w * b.w;
    }
    h1[i * 128 + o] = fmaxf(acc, 0.0f);
}

// ---------------- SAGE layer 2: h2 = relu(mean2@w2l^T + b2l + h1@w2r^T) ----------------
// block = 64 threads = one node
__global__ __launch_bounds__(64) void layer2_kernel(const float* __restrict__ h1,
                                                    const float* __restrict__ agg2,
                                                    const int* __restrict__ cnt,
                                                    const float* __restrict__ w2l,
                                                    const float* __restrict__ b2l,
                                                    const float* __restrict__ w2r,
                                                    float* __restrict__ h2) {
    int i = blockIdx.x;
    int o = threadIdx.x;  // 0..63
    __shared__ float hs[128], ms[128];
    float inv = 1.0f / fmaxf((float)cnt[i], 1.0f);
    hs[o]      = h1[i * 128 + o];
    hs[o + 64] = h1[i * 128 + o + 64];
    ms[o]      = agg2[i * 128 + o] * inv;
    ms[o + 64] = agg2[i * 128 + o + 64] * inv;
    __syncthreads();
    float acc = b2l[o];
    const float4* wl = (const float4*)(w2l + o * 128);
    const float4* wr = (const float4*)(w2r + o * 128);
    const float4* msv = (const float4*)ms;
    const float4* hsv = (const float4*)hs;
#pragma unroll
    for (int k = 0; k < 32; ++k) {
        float4 a = wl[k], b = wr[k];
        float4 m = msv[k], h = hsv[k];
        acc += m.x * a.x + m.y * a.y + m.z * a.z + m.w * a.w;
        acc += h.x * b.x + h.y * b.y + h.z * b.z + h.w * b.w;
    }
    h2[i * 64 + o] = fmaxf(acc, 0.0f);
}

// ---------------- per-node edge-MLP precompute ----------------
// u[i] = wc1[:, :64] @ h2[i] + bc1  (first half of each wc1 row)
// v[i] = wc1[:, 64:] @ h2[i]        (second half)
// block = 128 threads = one node (t<64 -> u, t>=64 -> v)
__global__ __launch_bounds__(128) void uv_kernel(const float* __restrict__ h2,
                                                 const float* __restrict__ wc1,
                                                 const float* __restrict__ bc1,
                                                 float* __restrict__ u,
                                                 float* __restrict__ v) {
    int i = blockIdx.x;
    int t = threadIdx.x;
    __shared__ float hs[64];
    if (t < 64) hs[t] = h2[i * 64 + t];
    __syncthreads();
    int o = t & 63;
    const float4* w = (const float4*)(wc1 + o * 128 + (t >> 6) * 64);
    const float4* hsv = (const float4*)hs;
    float acc = (t < 64) ? bc1[o] : 0.0f;
#pragma unroll
    for (int k = 0; k < 16; ++k) {
        float4 wv = w[k];
        float4 h = hsv[k];
        acc += wv.x * h.x + wv.y * h.y + wv.z * h.z + wv.w * h.w;
    }
    if (t < 64) u[i * 64 + o] = acc;
    else        v[i * 64 + o] = acc;
}

// ---------------- edge kernel: out = wc2 @ relu(u[src]+v[dst]) + bc2 ----------------
__global__ __launch_bounds__(256) void edge_kernel(const int* __restrict__ src,
                                                   const int* __restrict__ dst,
                                                   const float* __restrict__ u,
                                                   const float* __restrict__ v,
                                                   const float* __restrict__ wc2,
                                                   const float* __restrict__ bc2,
                                                   float* __restrict__ out) {
    int e = blockIdx.x * blockDim.x + threadIdx.x;
    if (e >= N_EDGES) return;
    const float4* up = (const float4*)(u + (size_t)src[e] * 64);
    const float4* vp = (const float4*)(v + (size_t)dst[e] * 64);
    const float4* w0 = (const float4*)(wc2);
    const float4* w1 = (const float4*)(wc2 + 64);
    float o0 = 0.0f, o1 = 0.0f;
#pragma unroll
    for (int k = 0; k < 16; ++k) {
        float4 a = up[k], b = vp[k];
        float4 c0 = w0[k], c1 = w1[k];
        float h;
        h = fmaxf(a.x + b.x, 0.0f); o0 += c0.x * h; o1 += c1.x * h;
        h = fmaxf(a.y + b.y, 0.0f); o0 += c0.y * h; o1 += c1.y * h;
        h = fmaxf(a.z + b.z, 0.0f); o0 += c0.z * h; o1 += c1.z * h;
        h = fmaxf(a.w + b.w, 0.0f); o0 += c0.w * h; o1 += c1.w * h;
    }
    float2 r;
    r.x = o0 + bc2[0];
    r.y = o1 + bc2[1];
    *(float2*)(out + (size_t)e * 2) = r;
}

extern "C" void kernel_launch(void* const* d_in, const int* in_sizes, int n_in,
                              void* d_out, int out_size, void* d_ws, size_t ws_size,
                              hipStream_t stream) {
    const float* x   = (const float*)d_in[0];
    const int*   ei  = (const int*)d_in[1];
    const float* w1l = (const float*)d_in[2];
    const float* b1l = (const float*)d_in[3];
    const float* w1r = (const float*)d_in[4];
    const float* w2l = (const float*)d_in[5];
    const float* b2l = (const float*)d_in[6];
    const float* w2r = (const float*)d_in[7];
    const float* wc1 = (const float*)d_in[8];
    const float* bc1 = (const float*)d_in[9];
    const float* wc2 = (const float*)d_in[10];
    const float* bc2 = (const float*)d_in[11];
    float* out = (float*)d_out;

    const int* srcp = ei;             // edge_index[0]
    const int* dstp = ei + N_EDGES;   // edge_index[1]

    // workspace layout (floats)
    float* ws   = (float*)d_ws;
    float* agg1 = ws;                  //  6,400,000 f32 (also reused as u)
    float* h1   = ws + 6400000;        // 12,800,000 f32
    float* agg2 = ws + 19200000;       // 12,800,000 f32 (also reused as v)
    float* h2   = ws + 32000000;       //  6,400,000 f32
    int*   cnt  = (int*)(ws + 38400000); // 100,000 i32
    float* u    = agg1;
    float* v    = agg2;

    hipMemsetAsync(agg1, 0, (size_t)6400000 * 4, stream);
    hipMemsetAsync(agg2, 0, (size_t)12800000 * 4, stream);
    hipMemsetAsync(cnt, 0, (size_t)N_NODES * 4, stream);

    degree_kernel<<<(N_EDGES + 255) / 256, 256, 0, stream>>>(dstp, cnt);

    scatter_kernel<6><<<(N_EDGES * 64 + 255) / 256, 256, 0, stream>>>(srcp, dstp, x, agg1);
    layer1_kernel<<<N_NODES, 128, 0, stream>>>(x, agg1, cnt, w1l, b1l, w1r, h1);

    scatter_kernel<7><<<(N_EDGES / 2 * 128 + 127) / 128, 256, 0, stream>>>(srcp, dstp, h1, agg2);
    layer2_kernel<<<N_NODES, 64, 0, stream>>>(h1, agg2, cnt, w2l, b2l, w2r, h2);

    uv_kernel<<<N_NODES, 128, 0, stream>>>(h2, wc1, bc1, u, v);

    edge_kernel<<<(N_EDGES + 255) / 256, 256, 0, stream>>>(srcp, dstp, u, v, wc2, bc2, out);
}

// Round 2
// 1486.032 us; speedup vs baseline: 2.0071x; 2.0071x over previous
//
#include <hip/hip_runtime.h>

#define N_NODES 100000
#define N_EDGES 1600000

// ---------------- degree count ----------------
__global__ __launch_bounds__(256) void degree_kernel(const int* __restrict__ dst,
                                                     int* __restrict__ cnt) {
    int e = blockIdx.x * blockDim.x + threadIdx.x;
    if (e < N_EDGES) atomicAdd(&cnt[dst[e]], 1);
}

// ---------------- scatter-add of D-dim features (D = 1<<LOGD) ----------------
template <int LOGD>
__global__ __launch_bounds__(256) void scatter_kernel(const int* __restrict__ src,
                                                      const int* __restrict__ dst,
                                                      const float* __restrict__ feat,
                                                      float* __restrict__ agg) {
    const int D = 1 << LOGD;
    int tid = blockIdx.x * blockDim.x + threadIdx.x;
    if (tid >= N_EDGES * D) return;
    int e = tid >> LOGD;
    int f = tid & (D - 1);
    int s = src[e], d = dst[e];
    unsafeAtomicAdd(&agg[d * D + f], feat[s * D + f]);
}

// ---------------- fused node transform (mini-GEMM, LDS-staged transposed weights) --------
// out[i][o] = act( sum_k A[i][k]*WA[o][k]  (+ sum_k (B[i][k]*inv_i)*WB[o][k])  + bias[o] )
// MODE 0: layer1 (A=x K=64,  B=agg1 K=64,  NOUT=128, relu, full bias)
// MODE 1: layer2 (A=h1 K=128, B=agg2 K=128, NOUT=64, relu, full bias)
// MODE 2: uv     (A=h2 K=64,  no B,        NOUT=128, no relu, bias on first 64 only,
//                 W[o][k] = o<64 ? wc1[o][k] : wc1[o-64][64+k])
template <int KC, int NOUT, int NPB, int MODE>
__global__ __launch_bounds__(256) void transform_kernel(
    const float* __restrict__ A,
    const float* __restrict__ B,
    const int* __restrict__ cnt,
    const float* __restrict__ WA,
    const float* __restrict__ WB,
    const float* __restrict__ bias,
    float* __restrict__ out)
{
    constexpr int NP  = NOUT + 4;       // padded wT row stride (keeps float4 alignment)
    constexpr int KP  = KC + 4;         // padded input row stride
    constexpr int NV  = NOUT / 4;       // float4 output columns
    constexpr int TN  = 256 / NV;       // threads along node dim
    constexpr int NPT = NPB / TN;       // nodes per thread
    constexpr int NCHUNK = (MODE == 2) ? 1 : 2;

    __shared__ float wT[KC * NP];       // transposed weights for current chunk
    __shared__ float ins[NPB * KP];     // staged inputs for current chunk
    __shared__ float bs[NOUT];
    __shared__ float invs[NPB];

    const int t    = threadIdx.x;
    const int base = blockIdx.x * NPB;
    const int tx   = t % NV;            // which float4 of outputs
    const int ty   = t / NV;            // node sub-index

    if (t < NOUT) {
        if (MODE == 2) bs[t] = (t < 64) ? bias[t] : 0.0f;
        else           bs[t] = bias[t];
    }
    if (NCHUNK == 2 && t < NPB) {
        int gn = base + t;
        invs[t] = (gn < N_NODES) ? 1.0f / fmaxf((float)cnt[gn], 1.0f) : 0.0f;
    }

    float4 acc[NPT];
#pragma unroll
    for (int j = 0; j < NPT; ++j) acc[j] = make_float4(0.f, 0.f, 0.f, 0.f);

    for (int c = 0; c < NCHUNK; ++c) {
        __syncthreads();  // protects wT/ins reuse between chunks (and covers bs/invs init)

        // stage weights transposed: wT[k][o] = W[o][k]; global reads coalesced
        for (int idx = t; idx < KC * NOUT; idx += 256) {
            int o = idx / KC, k = idx % KC;
            float w;
            if (MODE == 2) {
                w = WA[(o & 63) * 128 + ((o >> 6) << 6) + k];
            } else {
                const float* W = (c == 0) ? WA : WB;
                w = W[o * KC + k];
            }
            wT[k * NP + o] = w;
        }
        // stage inputs (chunk 1 scaled by 1/deg)
        {
            const float* S = (c == 0) ? A : B;
            for (int idx = t; idx < NPB * KC; idx += 256) {
                int n = idx / KC, k = idx % KC;
                int gn = base + n;
                float v = (gn < N_NODES) ? S[(size_t)gn * KC + k] : 0.0f;
                if (c == 1) v *= invs[n];
                ins[n * KP + k] = v;
            }
        }
        __syncthreads();

        for (int k = 0; k < KC; ++k) {
            float4 w4 = *(const float4*)&wT[k * NP + tx * 4];
#pragma unroll
            for (int j = 0; j < NPT; ++j) {
                float s = ins[(ty + j * TN) * KP + k];
                acc[j].x += s * w4.x;
                acc[j].y += s * w4.y;
                acc[j].z += s * w4.z;
                acc[j].w += s * w4.w;
            }
        }
    }

    // epilogue
    float4 bb = *(const float4*)&bs[tx * 4];
#pragma unroll
    for (int j = 0; j < NPT; ++j) {
        int gn = base + ty + j * TN;
        if (gn >= N_NODES) continue;
        float4 r = acc[j];
        r.x += bb.x; r.y += bb.y; r.z += bb.z; r.w += bb.w;
        if (MODE != 2) {
            r.x = fmaxf(r.x, 0.f); r.y = fmaxf(r.y, 0.f);
            r.z = fmaxf(r.z, 0.f); r.w = fmaxf(r.w, 0.f);
        }
        *(float4*)&out[(size_t)gn * NOUT + tx * 4] = r;
    }
}

// ---------------- edge kernel: out = wc2 @ relu(u[src]+v[dst]) + bc2 ----------------
// uv layout: per node 128 floats = [u(64) | v(64)]
__global__ __launch_bounds__(256) void edge_kernel(const int* __restrict__ src,
                                                   const int* __restrict__ dst,
                                                   const float* __restrict__ uv,
                                                   const float* __restrict__ wc2,
                                                   const float* __restrict__ bc2,
                                                   float* __restrict__ out) {
    int e = blockIdx.x * blockDim.x + threadIdx.x;
    if (e >= N_EDGES) return;
    const float4* up = (const float4*)(uv + (size_t)src[e] * 128);
    const float4* vp = (const float4*)(uv + (size_t)dst[e] * 128 + 64);
    const float4* w0 = (const float4*)(wc2);
    const float4* w1 = (const float4*)(wc2 + 64);
    float o0 = 0.0f, o1 = 0.0f;
#pragma unroll
    for (int k = 0; k < 16; ++k) {
        float4 a = up[k], b = vp[k];
        float4 c0 = w0[k], c1 = w1[k];
        float h;
        h = fmaxf(a.x + b.x, 0.0f); o0 += c0.x * h; o1 += c1.x * h;
        h = fmaxf(a.y + b.y, 0.0f); o0 += c0.y * h; o1 += c1.y * h;
        h = fmaxf(a.z + b.z, 0.0f); o0 += c0.z * h; o1 += c1.z * h;
        h = fmaxf(a.w + b.w, 0.0f); o0 += c0.w * h; o1 += c1.w * h;
    }
    float2 r;
    r.x = o0 + bc2[0];
    r.y = o1 + bc2[1];
    *(float2*)(out + (size_t)e * 2) = r;
}

extern "C" void kernel_launch(void* const* d_in, const int* in_sizes, int n_in,
                              void* d_out, int out_size, void* d_ws, size_t ws_size,
                              hipStream_t stream) {
    const float* x   = (const float*)d_in[0];
    const int*   ei  = (const int*)d_in[1];
    const float* w1l = (const float*)d_in[2];
    const float* b1l = (const float*)d_in[3];
    const float* w1r = (const float*)d_in[4];
    const float* w2l = (const float*)d_in[5];
    const float* b2l = (const float*)d_in[6];
    const float* w2r = (const float*)d_in[7];
    const float* wc1 = (const float*)d_in[8];
    const float* bc1 = (const float*)d_in[9];
    const float* wc2 = (const float*)d_in[10];
    const float* bc2 = (const float*)d_in[11];
    float* out = (float*)d_out;

    const int* srcp = ei;             // edge_index[0]
    const int* dstp = ei + N_EDGES;   // edge_index[1]

    // workspace layout (floats)
    float* ws   = (float*)d_ws;
    float* agg1 = ws;                    //  6,400,000 f32
    float* h1   = ws + 6400000;          // 12,800,000 f32 (reused as uv after layer2)
    float* agg2 = ws + 19200000;         // 12,800,000 f32
    float* h2   = ws + 32000000;         //  6,400,000 f32
    int*   cnt  = (int*)(ws + 38400000); // 100,000 i32
    float* uv   = h1;                    // alias: h1 dead once h2 computed

    hipMemsetAsync(agg1, 0, (size_t)6400000 * 4, stream);
    hipMemsetAsync(agg2, 0, (size_t)12800000 * 4, stream);
    hipMemsetAsync(cnt, 0, (size_t)N_NODES * 4, stream);

    degree_kernel<<<(N_EDGES + 255) / 256, 256, 0, stream>>>(dstp, cnt);

    scatter_kernel<6><<<(N_EDGES * 64) / 256, 256, 0, stream>>>(srcp, dstp, x, agg1);

    const int NB = (N_NODES + 63) / 64;  // 1563
    transform_kernel<64, 128, 64, 0><<<NB, 256, 0, stream>>>(x, agg1, cnt, w1r, w1l, b1l, h1);

    scatter_kernel<7><<<(N_EDGES * 128) / 256, 256, 0, stream>>>(srcp, dstp, h1, agg2);

    transform_kernel<128, 64, 64, 1><<<NB, 256, 0, stream>>>(h1, agg2, cnt, w2r, w2l, b2l, h2);

    transform_kernel<64, 128, 64, 2><<<NB, 256, 0, stream>>>(h2, nullptr, nullptr, wc1, nullptr, bc1, uv);

    edge_kernel<<<(N_EDGES + 255) / 256, 256, 0, stream>>>(srcp, dstp, uv, wc2, bc2, out);
}

// Round 3
// 725.177 us; speedup vs baseline: 4.1129x; 2.0492x over previous
//
#include <hip/hip_runtime.h>

#define N_NODES 100000
#define N_EDGES 1600000
#define NBLK_SCAN 391  // ceil(N_NODES/256)

// ---------------- degree count ----------------
__global__ __launch_bounds__(256) void degree_kernel(const int* __restrict__ dst,
                                                     int* __restrict__ cnt) {
    int e = blockIdx.x * blockDim.x + threadIdx.x;
    if (e < N_EDGES) atomicAdd(&cnt[dst[e]], 1);
}

// ---------------- scan step 1: per-block sums of cnt ----------------
__global__ __launch_bounds__(256) void scan_block_sums(const int* __restrict__ cnt,
                                                       int* __restrict__ partial) {
    __shared__ int red[4];
    int i = blockIdx.x * 256 + threadIdx.x;
    int v = (i < N_NODES) ? cnt[i] : 0;
#pragma unroll
    for (int off = 32; off; off >>= 1) v += __shfl_down(v, off, 64);
    if ((threadIdx.x & 63) == 0) red[threadIdx.x >> 6] = v;
    __syncthreads();
    if (threadIdx.x == 0) partial[blockIdx.x] = red[0] + red[1] + red[2] + red[3];
}

// ---------------- scan step 2: exclusive scan of partials (1 block) ----------------
__global__ __launch_bounds__(512) void scan_top(int* __restrict__ partial) {
    __shared__ int s[512];
    int t = threadIdx.x;
    int orig = (t < NBLK_SCAN) ? partial[t] : 0;
    s[t] = orig;
    __syncthreads();
#pragma unroll
    for (int off = 1; off < 512; off <<= 1) {
        int v = (t >= off) ? s[t - off] : 0;
        __syncthreads();
        s[t] += v;
        __syncthreads();
    }
    if (t < NBLK_SCAN) partial[t] = s[t] - orig;  // exclusive
}

// ---------------- scan step 3: row_start = excl scan, init cursor ----------------
__global__ __launch_bounds__(256) void scan_final(const int* __restrict__ cnt,
                                                  const int* __restrict__ partial,
                                                  int* __restrict__ row_start,
                                                  int* __restrict__ cursor) {
    __shared__ int s[256];
    int i = blockIdx.x * 256 + threadIdx.x;
    int t = threadIdx.x;
    int orig = (i < N_NODES) ? cnt[i] : 0;
    s[t] = orig;
    __syncthreads();
#pragma unroll
    for (int off = 1; off < 256; off <<= 1) {
        int v = (t >= off) ? s[t - off] : 0;
        __syncthreads();
        s[t] += v;
        __syncthreads();
    }
    if (i < N_NODES) {
        int rs = partial[blockIdx.x] + s[t] - orig;
        row_start[i] = rs;
        cursor[i] = rs;
    }
}

// ---------------- CSR fill ----------------
__global__ __launch_bounds__(256) void fill_kernel(const int* __restrict__ src,
                                                   const int* __restrict__ dst,
                                                   int* __restrict__ cursor,
                                                   int* __restrict__ nbr) {
    int e = blockIdx.x * blockDim.x + threadIdx.x;
    if (e < N_EDGES) {
        int pos = atomicAdd(&cursor[dst[e]], 1);
        nbr[pos] = src[e];
    }
}

// ---------------- gather-mean aggregation, D=64, one wave per node ----------------
__global__ __launch_bounds__(256) void agg_mean64_kernel(const int* __restrict__ row_start,
                                                         const int* __restrict__ cnt,
                                                         const int* __restrict__ nbr,
                                                         const float* __restrict__ feat,
                                                         float* __restrict__ outmean) {
    int node = blockIdx.x * 4 + (threadIdx.x >> 6);
    if (node >= N_NODES) return;
    int lane = threadIdx.x & 63;
    int s = row_start[node];
    int d = cnt[node];
    float acc = 0.0f;
    int p = 0;
    for (; p + 4 <= d; p += 4) {
        int n0 = nbr[s + p];
        int n1 = nbr[s + p + 1];
        int n2 = nbr[s + p + 2];
        int n3 = nbr[s + p + 3];
        float a0 = feat[(size_t)n0 * 64 + lane];
        float a1 = feat[(size_t)n1 * 64 + lane];
        float a2 = feat[(size_t)n2 * 64 + lane];
        float a3 = feat[(size_t)n3 * 64 + lane];
        acc += a0; acc += a1; acc += a2; acc += a3;
    }
    for (; p < d; ++p) acc += feat[(size_t)nbr[s + p] * 64 + lane];
    outmean[(size_t)node * 64 + lane] = acc / fmaxf((float)d, 1.0f);
}

// ---------------- fused node transform (mini-GEMM, LDS-staged transposed weights) --------
// MODE 0: out = relu(A@WA^T + B@WB^T + bias)            (layer1: A=x/w1r, B=mean1/w1l)
// MODE 1: out = A@WA^T                                   (y2 = h1@w2l^T)
// MODE 2: out = A@WA'^T + [bias|0]   WA'[o][k] = wc1[o&63][((o>>6)<<6)+k]   (uv)
// MODE 3: out = relu(A@WA^T + B + bias)                  (h2: B = mean2 addend [N,NOUT])
template <int KC, int NOUT, int MODE>
__global__ __launch_bounds__(256) void transform_kernel(
    const float* __restrict__ A,
    const float* __restrict__ B,
    const float* __restrict__ WA,
    const float* __restrict__ WB,
    const float* __restrict__ bias,
    float* __restrict__ out)
{
    constexpr int NPB = 64;
    constexpr int NP  = NOUT + 4;
    constexpr int KP  = KC + 4;
    constexpr int NV  = NOUT / 4;
    constexpr int TN  = 256 / NV;
    constexpr int NPT = NPB / TN;
    constexpr int NCHUNK = (MODE == 0) ? 2 : 1;

    __shared__ float wT[KC * NP];
    __shared__ float ins[NPB * KP];
    __shared__ float bs[NOUT];

    const int t    = threadIdx.x;
    const int base = blockIdx.x * NPB;
    const int tx   = t % NV;
    const int ty   = t / NV;

    if (t < NOUT) {
        if (MODE == 1)      bs[t] = 0.0f;
        else if (MODE == 2) bs[t] = (t < 64) ? bias[t] : 0.0f;
        else                bs[t] = bias[t];
    }

    float4 acc[NPT];
#pragma unroll
    for (int j = 0; j < NPT; ++j) acc[j] = make_float4(0.f, 0.f, 0.f, 0.f);

    for (int c = 0; c < NCHUNK; ++c) {
        __syncthreads();
        for (int idx = t; idx < KC * NOUT; idx += 256) {
            int o = idx / KC, k = idx % KC;
            float w;
            if (MODE == 2) w = WA[(o & 63) * 128 + ((o >> 6) << 6) + k];
            else           w = ((NCHUNK == 2 && c == 1) ? WB : WA)[o * KC + k];
            wT[k * NP + o] = w;
        }
        const float* S = (NCHUNK == 2 && c == 1) ? B : A;
        for (int idx = t; idx < NPB * KC; idx += 256) {
            int n = idx / KC, k = idx % KC;
            int gn = base + n;
            ins[n * KP + k] = (gn < N_NODES) ? S[(size_t)gn * KC + k] : 0.0f;
        }
        __syncthreads();
        for (int k = 0; k < KC; ++k) {
            float4 w4 = *(const float4*)&wT[k * NP + tx * 4];
#pragma unroll
            for (int j = 0; j < NPT; ++j) {
                float sv = ins[(ty + j * TN) * KP + k];
                acc[j].x += sv * w4.x;
                acc[j].y += sv * w4.y;
                acc[j].z += sv * w4.z;
                acc[j].w += sv * w4.w;
            }
        }
    }

    float4 bb = *(const float4*)&bs[tx * 4];
#pragma unroll
    for (int j = 0; j < NPT; ++j) {
        int gn = base + ty + j * TN;
        if (gn >= N_NODES) continue;
        float4 r = acc[j];
        r.x += bb.x; r.y += bb.y; r.z += bb.z; r.w += bb.w;
        if (MODE == 3) {
            float4 ad = *(const float4*)&B[(size_t)gn * NOUT + tx * 4];
            r.x += ad.x; r.y += ad.y; r.z += ad.z; r.w += ad.w;
        }
        if (MODE == 0 || MODE == 3) {
            r.x = fmaxf(r.x, 0.f); r.y = fmaxf(r.y, 0.f);
            r.z = fmaxf(r.z, 0.f); r.w = fmaxf(r.w, 0.f);
        }
        *(float4*)&out[(size_t)gn * NOUT + tx * 4] = r;
    }
}

// ---------------- edge kernel: out = wc2 @ relu(u[src]+v[dst]) + bc2 ----------------
// uv layout: per node 128 floats = [u(64) | v(64)]
__global__ __launch_bounds__(256) void edge_kernel(const int* __restrict__ src,
                                                   const int* __restrict__ dst,
                                                   const float* __restrict__ uv,
                                                   const float* __restrict__ wc2,
                                                   const float* __restrict__ bc2,
                                                   float* __restrict__ out) {
    int e = blockIdx.x * blockDim.x + threadIdx.x;
    if (e >= N_EDGES) return;
    const float4* up = (const float4*)(uv + (size_t)src[e] * 128);
    const float4* vp = (const float4*)(uv + (size_t)dst[e] * 128 + 64);
    const float4* w0 = (const float4*)(wc2);
    const float4* w1 = (const float4*)(wc2 + 64);
    float o0 = 0.0f, o1 = 0.0f;
#pragma unroll
    for (int k = 0; k < 16; ++k) {
        float4 a = up[k], b = vp[k];
        float4 c0 = w0[k], c1 = w1[k];
        float h;
        h = fmaxf(a.x + b.x, 0.0f); o0 += c0.x * h; o1 += c1.x * h;
        h = fmaxf(a.y + b.y, 0.0f); o0 += c0.y * h; o1 += c1.y * h;
        h = fmaxf(a.z + b.z, 0.0f); o0 += c0.z * h; o1 += c1.z * h;
        h = fmaxf(a.w + b.w, 0.0f); o0 += c0.w * h; o1 += c1.w * h;
    }
    float2 r;
    r.x = o0 + bc2[0];
    r.y = o1 + bc2[1];
    *(float2*)(out + (size_t)e * 2) = r;
}

extern "C" void kernel_launch(void* const* d_in, const int* in_sizes, int n_in,
                              void* d_out, int out_size, void* d_ws, size_t ws_size,
                              hipStream_t stream) {
    const float* x   = (const float*)d_in[0];
    const int*   ei  = (const int*)d_in[1];
    const float* w1l = (const float*)d_in[2];
    const float* b1l = (const float*)d_in[3];
    const float* w1r = (const float*)d_in[4];
    const float* w2l = (const float*)d_in[5];
    const float* b2l = (const float*)d_in[6];
    const float* w2r = (const float*)d_in[7];
    const float* wc1 = (const float*)d_in[8];
    const float* bc1 = (const float*)d_in[9];
    const float* wc2 = (const float*)d_in[10];
    const float* bc2 = (const float*)d_in[11];
    float* out = (float*)d_out;

    const int* srcp = ei;             // edge_index[0]
    const int* dstp = ei + N_EDGES;   // edge_index[1]

    // workspace layout
    float* ws    = (float*)d_ws;
    float* mean1 = ws;                   //  6.4e6 f32 (reused as y2)
    float* h1    = ws + 6400000;         // 12.8e6 f32 (reused as uv)
    float* mean2 = ws + 19200000;        //  6.4e6 f32
    float* h2    = ws + 25600000;        //  6.4e6 f32
    int*   ib    = (int*)(ws + 32000000);
    int* cnt       = ib;                 // 100000
    int* row_start = ib + 100000;        // 100000
    int* cursor    = ib + 200000;        // 100000
    int* partial   = ib + 300000;        // 512
    int* nbr       = ib + 300512;        // 1600000
    float* y2 = mean1;
    float* uv = h1;

    hipMemsetAsync(cnt, 0, (size_t)N_NODES * 4, stream);

    degree_kernel<<<(N_EDGES + 255) / 256, 256, 0, stream>>>(dstp, cnt);
    scan_block_sums<<<NBLK_SCAN, 256, 0, stream>>>(cnt, partial);
    scan_top<<<1, 512, 0, stream>>>(partial);
    scan_final<<<NBLK_SCAN, 256, 0, stream>>>(cnt, partial, row_start, cursor);
    fill_kernel<<<(N_EDGES + 255) / 256, 256, 0, stream>>>(srcp, dstp, cursor, nbr);

    const int NAB = (N_NODES + 3) / 4;    // agg blocks (4 nodes each)
    const int NB  = (N_NODES + 63) / 64;  // transform blocks

    // layer 1: mean-aggregate x, then fused transform
    agg_mean64_kernel<<<NAB, 256, 0, stream>>>(row_start, cnt, nbr, x, mean1);
    transform_kernel<64, 128, 0><<<NB, 256, 0, stream>>>(x, mean1, w1r, w1l, b1l, h1);

    // layer 2: y2 = h1@w2l^T, aggregate y2 (64-dim), then h2 = relu(h1@w2r^T + mean2 + b2l)
    transform_kernel<128, 64, 1><<<NB, 256, 0, stream>>>(h1, nullptr, w2l, nullptr, nullptr, y2);
    agg_mean64_kernel<<<NAB, 256, 0, stream>>>(row_start, cnt, nbr, y2, mean2);
    transform_kernel<128, 64, 3><<<NB, 256, 0, stream>>>(h1, mean2, w2r, nullptr, b2l, h2);

    // edge MLP precompute + edge kernel
    transform_kernel<64, 128, 2><<<NB, 256, 0, stream>>>(h2, nullptr, wc1, nullptr, bc1, uv);
    edge_kernel<<<(N_EDGES + 255) / 256, 256, 0, stream>>>(srcp, dstp, uv, wc2, bc2, out);
}

// Round 4
// 606.799 us; speedup vs baseline: 4.9153x; 1.1951x over previous
//
#include <hip/hip_runtime.h>

#define N_NODES 100000
#define N_EDGES 1600000
#define NBLK_SCAN 391  // ceil(N_NODES/256)

typedef unsigned int uint;
typedef unsigned short ushort;

__device__ inline float bflo(uint u) { union { uint i; float f; } c; c.i = u << 16; return c.f; }
__device__ inline float bfhi(uint u) { union { uint i; float f; } c; c.i = u & 0xffff0000u; return c.f; }
__device__ inline ushort f2bf(float f) {
    union { float f; uint u; } c; c.f = f;
    uint r = (c.u + 0x7fffu + ((c.u >> 16) & 1u)) >> 16;
    return (ushort)r;
}
__device__ inline ushort4 f4tobf(float4 v) {
    ushort4 o; o.x = f2bf(v.x); o.y = f2bf(v.y); o.z = f2bf(v.z); o.w = f2bf(v.w); return o;
}

// ---------------- f32 -> bf16 convert (x) ----------------
__global__ __launch_bounds__(256) void convert_kernel(const float* __restrict__ x,
                                                      ushort* __restrict__ xb) {
    int i = blockIdx.x * 256 + threadIdx.x;  // one float2 -> one packed uint
    if (i < N_NODES * 32) {
        float2 v = ((const float2*)x)[i];
        uint o = (uint)f2bf(v.x) | ((uint)f2bf(v.y) << 16);
        ((uint*)xb)[i] = o;
    }
}

// ---------------- degree count ----------------
__global__ __launch_bounds__(256) void degree_kernel(const int* __restrict__ dst,
                                                     int* __restrict__ cnt) {
    int e = blockIdx.x * blockDim.x + threadIdx.x;
    if (e < N_EDGES) atomicAdd(&cnt[dst[e]], 1);
}

// ---------------- scan step 1: per-block sums of cnt ----------------
__global__ __launch_bounds__(256) void scan_block_sums(const int* __restrict__ cnt,
                                                       int* __restrict__ partial) {
    __shared__ int red[4];
    int i = blockIdx.x * 256 + threadIdx.x;
    int v = (i < N_NODES) ? cnt[i] : 0;
#pragma unroll
    for (int off = 32; off; off >>= 1) v += __shfl_down(v, off, 64);
    if ((threadIdx.x & 63) == 0) red[threadIdx.x >> 6] = v;
    __syncthreads();
    if (threadIdx.x == 0) partial[blockIdx.x] = red[0] + red[1] + red[2] + red[3];
}

// ---------------- scan step 2: exclusive scan of partials (1 block) ----------------
__global__ __launch_bounds__(512) void scan_top(int* __restrict__ partial) {
    __shared__ int s[512];
    int t = threadIdx.x;
    int orig = (t < NBLK_SCAN) ? partial[t] : 0;
    s[t] = orig;
    __syncthreads();
#pragma unroll
    for (int off = 1; off < 512; off <<= 1) {
        int v = (t >= off) ? s[t - off] : 0;
        __syncthreads();
        s[t] += v;
        __syncthreads();
    }
    if (t < NBLK_SCAN) partial[t] = s[t] - orig;  // exclusive
}

// ---------------- scan step 3: row_start = excl scan, init cursor ----------------
__global__ __launch_bounds__(256) void scan_final(const int* __restrict__ cnt,
                                                  const int* __restrict__ partial,
                                                  int* __restrict__ row_start,
                                                  int* __restrict__ cursor) {
    __shared__ int s[256];
    int i = blockIdx.x * 256 + threadIdx.x;
    int t = threadIdx.x;
    int orig = (i < N_NODES) ? cnt[i] : 0;
    s[t] = orig;
    __syncthreads();
#pragma unroll
    for (int off = 1; off < 256; off <<= 1) {
        int v = (t >= off) ? s[t - off] : 0;
        __syncthreads();
        s[t] += v;
        __syncthreads();
    }
    if (i < N_NODES) {
        int rs = partial[blockIdx.x] + s[t] - orig;
        row_start[i] = rs;
        cursor[i] = rs;
    }
}

// ---------------- CSR fill ----------------
__global__ __launch_bounds__(256) void fill_kernel(const int* __restrict__ src,
                                                   const int* __restrict__ dst,
                                                   int* __restrict__ cursor,
                                                   int* __restrict__ nbr) {
    int e = blockIdx.x * blockDim.x + threadIdx.x;
    if (e < N_EDGES) {
        int pos = atomicAdd(&cursor[dst[e]], 1);
        nbr[pos] = src[e];
    }
}

// ---------------- gather-mean, bf16 features, D=64 ----------------
// one wave per node; lanes split in 2 halves, each half reads one neighbor's
// full 128 B row (32 lanes x bf16x2); halves combined via shfl_xor(32).
__global__ __launch_bounds__(256) void agg_mean64_bf16(const int* __restrict__ row_start,
                                                       const int* __restrict__ cnt,
                                                       const int* __restrict__ nbr,
                                                       const ushort* __restrict__ feat,
                                                       float* __restrict__ outmean) {
    int node = blockIdx.x * 4 + (threadIdx.x >> 6);
    if (node >= N_NODES) return;
    int lane = threadIdx.x & 63;
    int half = lane >> 5;       // 0/1: which neighbor of the pair
    int f2   = lane & 31;       // feature pair index
    int s = row_start[node];
    int d = cnt[node];
    float ax = 0.0f, ay = 0.0f;
    int p = 0;
    for (; p + 4 <= d; p += 4) {
        int n0 = nbr[s + p + half];
        int n1 = nbr[s + p + 2 + half];
        uint w0 = *(const uint*)(feat + (size_t)n0 * 64 + f2 * 2);
        uint w1 = *(const uint*)(feat + (size_t)n1 * 64 + f2 * 2);
        ax += bflo(w0) + bflo(w1);
        ay += bfhi(w0) + bfhi(w1);
    }
    for (; p + 2 <= d; p += 2) {
        int n0 = nbr[s + p + half];
        uint w0 = *(const uint*)(feat + (size_t)n0 * 64 + f2 * 2);
        ax += bflo(w0);
        ay += bfhi(w0);
    }
    if (p < d && half == 0) {
        int n0 = nbr[s + p];
        uint w0 = *(const uint*)(feat + (size_t)n0 * 64 + f2 * 2);
        ax += bflo(w0);
        ay += bfhi(w0);
    }
    ax += __shfl_xor(ax, 32, 64);
    ay += __shfl_xor(ay, 32, 64);
    if (half == 0) {
        float inv = 1.0f / fmaxf((float)d, 1.0f);
        float2 o; o.x = ax * inv; o.y = ay * inv;
        *(float2*)&outmean[(size_t)node * 64 + f2 * 2] = o;
    }
}

// ---------------- layer1 fused: h1 = relu(x@w1r^T + mean1@w1l^T + b1l); y2 = h1@w2l^T ----
// 64 nodes per block; h1 written f32 (needed by layer2), y2 written bf16 (gathered by agg2)
__global__ __launch_bounds__(256) void layer1_fused(const float* __restrict__ x,
                                                    const float* __restrict__ mean1,
                                                    const float* __restrict__ w1r,
                                                    const float* __restrict__ w1l,
                                                    const float* __restrict__ b1l,
                                                    const float* __restrict__ w2l,
                                                    float* __restrict__ h1,
                                                    ushort* __restrict__ y2b) {
    __shared__ float buf[17152];
    __shared__ float bs[128];
    float* wTa  = buf;          // [64][132]  phase A weights
    float* insa = buf + 8448;   // [64][68]   phase A inputs
    float* insb = buf;          // [64][132]  phase B inputs (h1), overlays wTa
    float* wTb  = buf + 8448;   // [128][68]  phase B weights, overlays insa

    const int t = threadIdx.x;
    const int base = blockIdx.x * 64;
    const int tx = t & 31, ty = t >> 5;    // phase A: NOUT=128

    if (t < 128) bs[t] = b1l[t];

    float4 acc[8];
#pragma unroll
    for (int j = 0; j < 8; ++j) acc[j] = make_float4(0.f, 0.f, 0.f, 0.f);

    for (int c = 0; c < 2; ++c) {
        __syncthreads();
        const float* W = c ? w1l : w1r;
        for (int idx = t; idx < 8192; idx += 256) {
            int o = idx >> 6, k = idx & 63;
            wTa[k * 132 + o] = W[o * 64 + k];
        }
        const float* S = c ? mean1 : x;
        for (int idx = t; idx < 4096; idx += 256) {
            int n = idx >> 6, k = idx & 63;
            int gn = base + n;
            insa[n * 68 + k] = (gn < N_NODES) ? S[(size_t)gn * 64 + k] : 0.0f;
        }
        __syncthreads();
        for (int k = 0; k < 64; ++k) {
            float4 w4 = *(const float4*)&wTa[k * 132 + tx * 4];
#pragma unroll
            for (int j = 0; j < 8; ++j) {
                float sv = insa[(ty + j * 8) * 68 + k];
                acc[j].x += sv * w4.x; acc[j].y += sv * w4.y;
                acc[j].z += sv * w4.z; acc[j].w += sv * w4.w;
            }
        }
    }
    __syncthreads();  // done reading wTa/insa
    // epilogue A: bias + relu -> h1 global + insb
    {
        float4 bb = *(const float4*)&bs[tx * 4];
#pragma unroll
        for (int j = 0; j < 8; ++j) {
            int n = ty + j * 8;
            int gn = base + n;
            float4 r = acc[j];
            r.x = fmaxf(r.x + bb.x, 0.f); r.y = fmaxf(r.y + bb.y, 0.f);
            r.z = fmaxf(r.z + bb.z, 0.f); r.w = fmaxf(r.w + bb.w, 0.f);
            *(float4*)&insb[n * 132 + tx * 4] = r;
            if (gn < N_NODES) *(float4*)&h1[(size_t)gn * 128 + tx * 4] = r;
        }
    }
    // stage w2l transposed: wTb[k][o] = w2l[o][k]
    for (int idx = t; idx < 8192; idx += 256) {
        int o = idx >> 7, k = idx & 127;
        wTb[k * 68 + o] = w2l[o * 128 + k];
    }
    __syncthreads();
    // phase B: y2 = h1@w2l^T  (NOUT=64)
    const int tx2 = t & 15, ty2 = t >> 4;
    float4 acc2[4];
#pragma unroll
    for (int j = 0; j < 4; ++j) acc2[j] = make_float4(0.f, 0.f, 0.f, 0.f);
    for (int k = 0; k < 128; ++k) {
        float4 w4 = *(const float4*)&wTb[k * 68 + tx2 * 4];
#pragma unroll
        for (int j = 0; j < 4; ++j) {
            float sv = insb[(ty2 + j * 16) * 132 + k];
            acc2[j].x += sv * w4.x; acc2[j].y += sv * w4.y;
            acc2[j].z += sv * w4.z; acc2[j].w += sv * w4.w;
        }
    }
#pragma unroll
    for (int j = 0; j < 4; ++j) {
        int gn = base + ty2 + j * 16;
        if (gn < N_NODES) *(ushort4*)&y2b[(size_t)gn * 64 + tx2 * 4] = f4tobf(acc2[j]);
    }
}

// ---------------- layer2+uv fused: h2 = relu(h1@w2r^T + mean2 + b2l); uv = h2@wc1'^T + [bc1|0]
// h2 never leaves LDS; uv written bf16 (gathered by edge kernel)
__global__ __launch_bounds__(256) void layer2_uv_fused(const float* __restrict__ h1,
                                                       const float* __restrict__ mean2,
                                                       const float* __restrict__ w2r,
                                                       const float* __restrict__ b2l,
                                                       const float* __restrict__ wc1,
                                                       const float* __restrict__ bc1,
                                                       ushort* __restrict__ uvb) {
    __shared__ float buf[17152];
    __shared__ float bsa[64];
    __shared__ float bsb[128];
    float* wTa  = buf;          // [128][68]
    float* insa = buf + 8704;   // [64][132]
    float* insb = buf;          // [64][68]   (h2), overlays wTa
    float* wTb  = buf + 8704;   // [64][132]  overlays insa

    const int t = threadIdx.x;
    const int base = blockIdx.x * 64;
    const int tx = t & 15, ty = t >> 4;    // phase A: NOUT=64

    if (t < 64)  bsa[t] = b2l[t];
    if (t < 128) bsb[t] = (t < 64) ? bc1[t] : 0.0f;

    // stage w2r^T and h1
    for (int idx = t; idx < 8192; idx += 256) {
        int o = idx >> 7, k = idx & 127;
        wTa[k * 68 + o] = w2r[o * 128 + k];
    }
    for (int idx = t; idx < 8192; idx += 256) {
        int n = idx >> 7, k = idx & 127;
        int gn = base + n;
        insa[n * 132 + k] = (gn < N_NODES) ? h1[(size_t)gn * 128 + k] : 0.0f;
    }
    __syncthreads();
    float4 acc[4];
#pragma unroll
    for (int j = 0; j < 4; ++j) acc[j] = make_float4(0.f, 0.f, 0.f, 0.f);
    for (int k = 0; k < 128; ++k) {
        float4 w4 = *(const float4*)&wTa[k * 68 + tx * 4];
#pragma unroll
        for (int j = 0; j < 4; ++j) {
            float sv = insa[(ty + j * 16) * 132 + k];
            acc[j].x += sv * w4.x; acc[j].y += sv * w4.y;
            acc[j].z += sv * w4.z; acc[j].w += sv * w4.w;
        }
    }
    __syncthreads();  // done reading wTa/insa
    // epilogue A: + mean2 + bias, relu -> insb (LDS only)
    {
        float4 bb = *(const float4*)&bsa[tx * 4];
#pragma unroll
        for (int j = 0; j < 4; ++j) {
            int n = ty + j * 16;
            int gn = base + n;
            float4 r = acc[j];
            if (gn < N_NODES) {
                float4 ad = *(const float4*)&mean2[(size_t)gn * 64 + tx * 4];
                r.x += ad.x; r.y += ad.y; r.z += ad.z; r.w += ad.w;
            }
            r.x = fmaxf(r.x + bb.x, 0.f); r.y = fmaxf(r.y + bb.y, 0.f);
            r.z = fmaxf(r.z + bb.z, 0.f); r.w = fmaxf(r.w + bb.w, 0.f);
            *(float4*)&insb[n * 68 + tx * 4] = r;
        }
    }
    // stage wc1' transposed: o<64 -> wc1[o][k] (u), o>=64 -> wc1[o-64][64+k] (v)
    for (int idx = t; idx < 8192; idx += 256) {
        int o = idx >> 6, k = idx & 63;
        wTb[k * 132 + o] = wc1[(o & 63) * 128 + ((o >> 6) << 6) + k];
    }
    __syncthreads();
    // phase B: uv = h2@wc1'^T (NOUT=128)
    const int tx2 = t & 31, ty2 = t >> 5;
    float4 acc2[8];
#pragma unroll
    for (int j = 0; j < 8; ++j) acc2[j] = make_float4(0.f, 0.f, 0.f, 0.f);
    for (int k = 0; k < 64; ++k) {
        float4 w4 = *(const float4*)&wTb[k * 132 + tx2 * 4];
#pragma unroll
        for (int j = 0; j < 8; ++j) {
            float sv = insb[(ty2 + j * 8) * 68 + k];
            acc2[j].x += sv * w4.x; acc2[j].y += sv * w4.y;
            acc2[j].z += sv * w4.z; acc2[j].w += sv * w4.w;
        }
    }
    {
        float4 bb = *(const float4*)&bsb[tx2 * 4];
#pragma unroll
        for (int j = 0; j < 8; ++j) {
            int gn = base + ty2 + j * 8;
            if (gn < N_NODES) {
                float4 r = acc2[j];
                r.x += bb.x; r.y += bb.y; r.z += bb.z; r.w += bb.w;
                *(ushort4*)&uvb[(size_t)gn * 128 + tx2 * 4] = f4tobf(r);
            }
        }
    }
}

// ---------------- edge kernel: out = wc2 @ relu(u[src]+v[dst]) + bc2, bf16 uv ---------
__global__ __launch_bounds__(256) void edge_kernel(const int* __restrict__ src,
                                                   const int* __restrict__ dst,
                                                   const ushort* __restrict__ uvb,
                                                   const float* __restrict__ wc2,
                                                   const float* __restrict__ bc2,
                                                   float* __restrict__ out) {
    int e = blockIdx.x * blockDim.x + threadIdx.x;
    if (e >= N_EDGES) return;
    const uint* ua = (const uint*)(uvb + (size_t)src[e] * 128);
    const uint* va = (const uint*)(uvb + (size_t)dst[e] * 128 + 64);
    float o0 = 0.0f, o1 = 0.0f;
#pragma unroll
    for (int k = 0; k < 32; ++k) {
        uint a = ua[k], b = va[k];
        float h0 = fmaxf(bflo(a) + bflo(b), 0.0f);
        float h1 = fmaxf(bfhi(a) + bfhi(b), 0.0f);
        o0 += wc2[2 * k] * h0 + wc2[2 * k + 1] * h1;
        o1 += wc2[64 + 2 * k] * h0 + wc2[65 + 2 * k] * h1;
    }
    float2 r;
    r.x = o0 + bc2[0];
    r.y = o1 + bc2[1];
    *(float2*)(out + (size_t)e * 2) = r;
}

extern "C" void kernel_launch(void* const* d_in, const int* in_sizes, int n_in,
                              void* d_out, int out_size, void* d_ws, size_t ws_size,
                              hipStream_t stream) {
    const float* x   = (const float*)d_in[0];
    const int*   ei  = (const int*)d_in[1];
    const float* w1l = (const float*)d_in[2];
    const float* b1l = (const float*)d_in[3];
    const float* w1r = (const float*)d_in[4];
    const float* w2l = (const float*)d_in[5];
    const float* b2l = (const float*)d_in[6];
    const float* w2r = (const float*)d_in[7];
    const float* wc1 = (const float*)d_in[8];
    const float* bc1 = (const float*)d_in[9];
    const float* wc2 = (const float*)d_in[10];
    const float* bc2 = (const float*)d_in[11];
    float* out = (float*)d_out;

    const int* srcp = ei;             // edge_index[0]
    const int* dstp = ei + N_EDGES;   // edge_index[1]

    // workspace layout (f32 slots); xb/y2b share, mean1/uvb share (liveness disjoint)
    float*  ws    = (float*)d_ws;
    ushort* xb    = (ushort*)ws;                 // [0, 3.2M)  6.4M bf16
    ushort* y2b   = (ushort*)ws;                 //            (alias, after agg1)
    float*  mean1 = ws + 3200000;                // [3.2M, 9.6M)
    ushort* uvb   = (ushort*)(ws + 3200000);     //            (alias, after layer1)
    float*  h1    = ws + 9600000;                // [9.6M, 22.4M)
    float*  mean2 = ws + 22400000;               // [22.4M, 28.8M)
    int*    ib    = (int*)(ws + 28800000);
    int* cnt       = ib;                 // 100000
    int* row_start = ib + 100000;        // 100000
    int* cursor    = ib + 200000;        // 100000
    int* partial   = ib + 300000;        // 512
    int* nbr       = ib + 300512;        // 1600000

    hipMemsetAsync(cnt, 0, (size_t)N_NODES * 4, stream);

    convert_kernel<<<12500, 256, 0, stream>>>(x, xb);
    degree_kernel<<<(N_EDGES + 255) / 256, 256, 0, stream>>>(dstp, cnt);
    scan_block_sums<<<NBLK_SCAN, 256, 0, stream>>>(cnt, partial);
    scan_top<<<1, 512, 0, stream>>>(partial);
    scan_final<<<NBLK_SCAN, 256, 0, stream>>>(cnt, partial, row_start, cursor);
    fill_kernel<<<(N_EDGES + 255) / 256, 256, 0, stream>>>(srcp, dstp, cursor, nbr);

    const int NAB = (N_NODES + 3) / 4;
    const int NB  = (N_NODES + 63) / 64;

    agg_mean64_bf16<<<NAB, 256, 0, stream>>>(row_start, cnt, nbr, xb, mean1);
    layer1_fused<<<NB, 256, 0, stream>>>(x, mean1, w1r, w1l, b1l, w2l, h1, y2b);
    agg_mean64_bf16<<<NAB, 256, 0, stream>>>(row_start, cnt, nbr, y2b, mean2);
    layer2_uv_fused<<<NB, 256, 0, stream>>>(h1, mean2, w2r, b2l, wc1, bc1, uvb);
    edge_kernel<<<(N_EDGES + 255) / 256, 256, 0, stream>>>(srcp, dstp, uvb, wc2, bc2, out);
}

// Round 5
// 558.562 us; speedup vs baseline: 5.3398x; 1.0864x over previous
//
#include <hip/hip_runtime.h>

#define N_NODES 100000
#define N_EDGES 1600000
#define NBLK_SCAN 391  // ceil(N_NODES/256)
#define SLICE_NODES 12500   // N_NODES/8
#define FILL_CHUNK 12500    // N_EDGES/128

typedef unsigned int uint;
typedef unsigned short ushort;

__device__ inline float bflo(uint u) { union { uint i; float f; } c; c.i = u << 16; return c.f; }
__device__ inline float bfhi(uint u) { union { uint i; float f; } c; c.i = u & 0xffff0000u; return c.f; }
__device__ inline ushort f2bf(float f) {
    union { float f; uint u; } c; c.f = f;
    uint r = (c.u + 0x7fffu + ((c.u >> 16) & 1u)) >> 16;
    return (ushort)r;
}
__device__ inline ushort4 f4tobf(float4 v) {
    ushort4 o; o.x = f2bf(v.x); o.y = f2bf(v.y); o.z = f2bf(v.z); o.w = f2bf(v.w); return o;
}

// ---------------- f32 -> bf16 convert (x) ----------------
__global__ __launch_bounds__(256) void convert_kernel(const float* __restrict__ x,
                                                      ushort* __restrict__ xb) {
    int i = blockIdx.x * 256 + threadIdx.x;  // one float2 -> one packed uint
    if (i < N_NODES * 32) {
        float2 v = ((const float2*)x)[i];
        uint o = (uint)f2bf(v.x) | ((uint)f2bf(v.y) << 16);
        ((uint*)xb)[i] = o;
    }
}

// ---------------- degree count ----------------
__global__ __launch_bounds__(256) void degree_kernel(const int* __restrict__ dst,
                                                     int* __restrict__ cnt) {
    int e = blockIdx.x * blockDim.x + threadIdx.x;
    if (e < N_EDGES) atomicAdd(&cnt[dst[e]], 1);
}

// ---------------- scan step 1: per-block sums of cnt ----------------
__global__ __launch_bounds__(256) void scan_block_sums(const int* __restrict__ cnt,
                                                       int* __restrict__ partial) {
    __shared__ int red[4];
    int i = blockIdx.x * 256 + threadIdx.x;
    int v = (i < N_NODES) ? cnt[i] : 0;
#pragma unroll
    for (int off = 32; off; off >>= 1) v += __shfl_down(v, off, 64);
    if ((threadIdx.x & 63) == 0) red[threadIdx.x >> 6] = v;
    __syncthreads();
    if (threadIdx.x == 0) partial[blockIdx.x] = red[0] + red[1] + red[2] + red[3];
}

// ---------------- scan step 2: exclusive scan of partials (1 block) ----------------
__global__ __launch_bounds__(512) void scan_top(int* __restrict__ partial) {
    __shared__ int s[512];
    int t = threadIdx.x;
    int orig = (t < NBLK_SCAN) ? partial[t] : 0;
    s[t] = orig;
    __syncthreads();
#pragma unroll
    for (int off = 1; off < 512; off <<= 1) {
        int v = (t >= off) ? s[t - off] : 0;
        __syncthreads();
        s[t] += v;
        __syncthreads();
    }
    if (t < NBLK_SCAN) partial[t] = s[t] - orig;  // exclusive
}

// ---------------- scan step 3: row_start = excl scan, init cursor ----------------
__global__ __launch_bounds__(256) void scan_final(const int* __restrict__ cnt,
                                                  const int* __restrict__ partial,
                                                  int* __restrict__ row_start,
                                                  int* __restrict__ cursor) {
    __shared__ int s[256];
    int i = blockIdx.x * 256 + threadIdx.x;
    int t = threadIdx.x;
    int orig = (i < N_NODES) ? cnt[i] : 0;
    s[t] = orig;
    __syncthreads();
#pragma unroll
    for (int off = 1; off < 256; off <<= 1) {
        int v = (t >= off) ? s[t - off] : 0;
        __syncthreads();
        s[t] += v;
        __syncthreads();
    }
    if (i < N_NODES) {
        int rs = partial[blockIdx.x] + s[t] - orig;
        row_start[i] = rs;
        cursor[i] = rs;
    }
}

// ---------------- CSR fill, XCD-sliced ----------------
// block b: dst-slice (b&7) [matches round-robin block->XCD], edge chunk (b>>3).
// Each slice's nbr region (~800 KB) is written only by one XCD's blocks ->
// lines fully dirtied in that XCD's L2 before writeback (kills 64B write-amp).
__global__ __launch_bounds__(256) void fill_sliced(const int* __restrict__ src,
                                                   const int* __restrict__ dst,
                                                   int* __restrict__ cursor,
                                                   int* __restrict__ nbr) {
    int slice = blockIdx.x & 7;
    int chunk = blockIdx.x >> 3;           // 0..127
    int lo = slice * SLICE_NODES;
    int hi = lo + SLICE_NODES;
    int ebase = chunk * FILL_CHUNK;
#pragma unroll 1
    for (int e = ebase + threadIdx.x; e < ebase + FILL_CHUNK; e += 256) {
        int d = dst[e];
        if (d >= lo && d < hi) {
            int pos = atomicAdd(&cursor[d], 1);
            nbr[pos] = src[e];
        }
    }
}

// ---------------- gather-mean, bf16 features, D=64 ----------------
// one wave per node; lanes split in 2 halves, each half reads one neighbor's
// full 128 B row (32 lanes x bf16x2); halves combined via shfl_xor(32).
__global__ __launch_bounds__(256) void agg_mean64_bf16(const int* __restrict__ row_start,
                                                       const int* __restrict__ cnt,
                                                       const int* __restrict__ nbr,
                                                       const ushort* __restrict__ feat,
                                                       float* __restrict__ outmean) {
    int node = blockIdx.x * 4 + (threadIdx.x >> 6);
    if (node >= N_NODES) return;
    int lane = threadIdx.x & 63;
    int half = lane >> 5;       // 0/1: which neighbor of the pair
    int f2   = lane & 31;       // feature pair index
    int s = row_start[node];
    int d = cnt[node];
    float ax = 0.0f, ay = 0.0f;
    int p = 0;
    for (; p + 4 <= d; p += 4) {
        int n0 = nbr[s + p + half];
        int n1 = nbr[s + p + 2 + half];
        uint w0 = *(const uint*)(feat + (size_t)n0 * 64 + f2 * 2);
        uint w1 = *(const uint*)(feat + (size_t)n1 * 64 + f2 * 2);
        ax += bflo(w0) + bflo(w1);
        ay += bfhi(w0) + bfhi(w1);
    }
    for (; p + 2 <= d; p += 2) {
        int n0 = nbr[s + p + half];
        uint w0 = *(const uint*)(feat + (size_t)n0 * 64 + f2 * 2);
        ax += bflo(w0);
        ay += bfhi(w0);
    }
    if (p < d && half == 0) {
        int n0 = nbr[s + p];
        uint w0 = *(const uint*)(feat + (size_t)n0 * 64 + f2 * 2);
        ax += bflo(w0);
        ay += bfhi(w0);
    }
    ax += __shfl_xor(ax, 32, 64);
    ay += __shfl_xor(ay, 32, 64);
    if (half == 0) {
        float inv = 1.0f / fmaxf((float)d, 1.0f);
        float2 o; o.x = ax * inv; o.y = ay * inv;
        *(float2*)&outmean[(size_t)node * 64 + f2 * 2] = o;
    }
}

// ---------------- layer1 fused: h1 = relu(x@w1r^T + mean1@w1l^T + b1l); y2 = h1@w2l^T ----
// 64 nodes per block; h1 written f32 (needed by layer2), y2 written bf16 (gathered by agg2)
__global__ __launch_bounds__(256) void layer1_fused(const float* __restrict__ x,
                                                    const float* __restrict__ mean1,
                                                    const float* __restrict__ w1r,
                                                    const float* __restrict__ w1l,
                                                    const float* __restrict__ b1l,
                                                    const float* __restrict__ w2l,
                                                    float* __restrict__ h1,
                                                    ushort* __restrict__ y2b) {
    __shared__ float buf[17152];
    __shared__ float bs[128];
    float* wTa  = buf;          // [64][132]  phase A weights
    float* insa = buf + 8448;   // [64][68]   phase A inputs
    float* insb = buf;          // [64][132]  phase B inputs (h1), overlays wTa
    float* wTb  = buf + 8448;   // [128][68]  phase B weights, overlays insa

    const int t = threadIdx.x;
    const int base = blockIdx.x * 64;
    const int tx = t & 31, ty = t >> 5;    // phase A: NOUT=128

    if (t < 128) bs[t] = b1l[t];

    float4 acc[8];
#pragma unroll
    for (int j = 0; j < 8; ++j) acc[j] = make_float4(0.f, 0.f, 0.f, 0.f);

    for (int c = 0; c < 2; ++c) {
        __syncthreads();
        const float* W = c ? w1l : w1r;
        for (int idx = t; idx < 8192; idx += 256) {
            int o = idx >> 6, k = idx & 63;
            wTa[k * 132 + o] = W[o * 64 + k];
        }
        const float* S = c ? mean1 : x;
        for (int idx = t; idx < 4096; idx += 256) {
            int n = idx >> 6, k = idx & 63;
            int gn = base + n;
            insa[n * 68 + k] = (gn < N_NODES) ? S[(size_t)gn * 64 + k] : 0.0f;
        }
        __syncthreads();
        for (int k = 0; k < 64; ++k) {
            float4 w4 = *(const float4*)&wTa[k * 132 + tx * 4];
#pragma unroll
            for (int j = 0; j < 8; ++j) {
                float sv = insa[(ty + j * 8) * 68 + k];
                acc[j].x += sv * w4.x; acc[j].y += sv * w4.y;
                acc[j].z += sv * w4.z; acc[j].w += sv * w4.w;
            }
        }
    }
    __syncthreads();  // done reading wTa/insa
    // epilogue A: bias + relu -> h1 global + insb
    {
        float4 bb = *(const float4*)&bs[tx * 4];
#pragma unroll
        for (int j = 0; j < 8; ++j) {
            int n = ty + j * 8;
            int gn = base + n;
            float4 r = acc[j];
            r.x = fmaxf(r.x + bb.x, 0.f); r.y = fmaxf(r.y + bb.y, 0.f);
            r.z = fmaxf(r.z + bb.z, 0.f); r.w = fmaxf(r.w + bb.w, 0.f);
            *(float4*)&insb[n * 132 + tx * 4] = r;
            if (gn < N_NODES) *(float4*)&h1[(size_t)gn * 128 + tx * 4] = r;
        }
    }
    // stage w2l transposed: wTb[k][o] = w2l[o][k]
    for (int idx = t; idx < 8192; idx += 256) {
        int o = idx >> 7, k = idx & 127;
        wTb[k * 68 + o] = w2l[o * 128 + k];
    }
    __syncthreads();
    // phase B: y2 = h1@w2l^T  (NOUT=64)
    const int tx2 = t & 15, ty2 = t >> 4;
    float4 acc2[4];
#pragma unroll
    for (int j = 0; j < 4; ++j) acc2[j] = make_float4(0.f, 0.f, 0.f, 0.f);
    for (int k = 0; k < 128; ++k) {
        float4 w4 = *(const float4*)&wTb[k * 68 + tx2 * 4];
#pragma unroll
        for (int j = 0; j < 4; ++j) {
            float sv = insb[(ty2 + j * 16) * 132 + k];
            acc2[j].x += sv * w4.x; acc2[j].y += sv * w4.y;
            acc2[j].z += sv * w4.z; acc2[j].w += sv * w4.w;
        }
    }
#pragma unroll
    for (int j = 0; j < 4; ++j) {
        int gn = base + ty2 + j * 16;
        if (gn < N_NODES) *(ushort4*)&y2b[(size_t)gn * 64 + tx2 * 4] = f4tobf(acc2[j]);
    }
}

// ---------------- layer2+uv fused: h2 = relu(h1@w2r^T + mean2 + b2l); uv = h2@wc1'^T + [bc1|0]
// h2 never leaves LDS; uv written bf16 (gathered by edge kernel)
__global__ __launch_bounds__(256) void layer2_uv_fused(const float* __restrict__ h1,
                                                       const float* __restrict__ mean2,
                                                       const float* __restrict__ w2r,
                                                       const float* __restrict__ b2l,
                                                       const float* __restrict__ wc1,
                                                       const float* __restrict__ bc1,
                                                       ushort* __restrict__ uvb) {
    __shared__ float buf[17152];
    __shared__ float bsa[64];
    __shared__ float bsb[128];
    float* wTa  = buf;          // [128][68]
    float* insa = buf + 8704;   // [64][132]
    float* insb = buf;          // [64][68]   (h2), overlays wTa
    float* wTb  = buf + 8704;   // [64][132]  overlays insa

    const int t = threadIdx.x;
    const int base = blockIdx.x * 64;
    const int tx = t & 15, ty = t >> 4;    // phase A: NOUT=64

    if (t < 64)  bsa[t] = b2l[t];
    if (t < 128) bsb[t] = (t < 64) ? bc1[t] : 0.0f;

    // stage w2r^T and h1
    for (int idx = t; idx < 8192; idx += 256) {
        int o = idx >> 7, k = idx & 127;
        wTa[k * 68 + o] = w2r[o * 128 + k];
    }
    for (int idx = t; idx < 8192; idx += 256) {
        int n = idx >> 7, k = idx & 127;
        int gn = base + n;
        insa[n * 132 + k] = (gn < N_NODES) ? h1[(size_t)gn * 128 + k] : 0.0f;
    }
    __syncthreads();
    float4 acc[4];
#pragma unroll
    for (int j = 0; j < 4; ++j) acc[j] = make_float4(0.f, 0.f, 0.f, 0.f);
    for (int k = 0; k < 128; ++k) {
        float4 w4 = *(const float4*)&wTa[k * 68 + tx * 4];
#pragma unroll
        for (int j = 0; j < 4; ++j) {
            float sv = insa[(ty + j * 16) * 132 + k];
            acc[j].x += sv * w4.x; acc[j].y += sv * w4.y;
            acc[j].z += sv * w4.z; acc[j].w += sv * w4.w;
        }
    }
    __syncthreads();  // done reading wTa/insa
    // epilogue A: + mean2 + bias, relu -> insb (LDS only)
    {
        float4 bb = *(const float4*)&bsa[tx * 4];
#pragma unroll
        for (int j = 0; j < 4; ++j) {
            int n = ty + j * 16;
            int gn = base + n;
            float4 r = acc[j];
            if (gn < N_NODES) {
                float4 ad = *(const float4*)&mean2[(size_t)gn * 64 + tx * 4];
                r.x += ad.x; r.y += ad.y; r.z += ad.z; r.w += ad.w;
            }
            r.x = fmaxf(r.x + bb.x, 0.f); r.y = fmaxf(r.y + bb.y, 0.f);
            r.z = fmaxf(r.z + bb.z, 0.f); r.w = fmaxf(r.w + bb.w, 0.f);
            *(float4*)&insb[n * 68 + tx * 4] = r;
        }
    }
    // stage wc1' transposed: o<64 -> wc1[o][k] (u), o>=64 -> wc1[o-64][64+k] (v)
    for (int idx = t; idx < 8192; idx += 256) {
        int o = idx >> 6, k = idx & 63;
        wTb[k * 132 + o] = wc1[(o & 63) * 128 + ((o >> 6) << 6) + k];
    }
    __syncthreads();
    // phase B: uv = h2@wc1'^T (NOUT=128)
    const int tx2 = t & 31, ty2 = t >> 5;
    float4 acc2[8];
#pragma unroll
    for (int j = 0; j < 8; ++j) acc2[j] = make_float4(0.f, 0.f, 0.f, 0.f);
    for (int k = 0; k < 64; ++k) {
        float4 w4 = *(const float4*)&wTb[k * 132 + tx2 * 4];
#pragma unroll
        for (int j = 0; j < 8; ++j) {
            float sv = insb[(ty2 + j * 8) * 68 + k];
            acc2[j].x += sv * w4.x; acc2[j].y += sv * w4.y;
            acc2[j].z += sv * w4.z; acc2[j].w += sv * w4.w;
        }
    }
    {
        float4 bb = *(const float4*)&bsb[tx2 * 4];
#pragma unroll
        for (int j = 0; j < 8; ++j) {
            int gn = base + ty2 + j * 8;
            if (gn < N_NODES) {
                float4 r = acc2[j];
                r.x += bb.x; r.y += bb.y; r.z += bb.z; r.w += bb.w;
                *(ushort4*)&uvb[(size_t)gn * 128 + tx2 * 4] = f4tobf(r);
            }
        }
    }
}

// ---------------- edge kernel: out = wc2 @ relu(u[src]+v[dst]) + bc2, bf16 uv ---------
__global__ __launch_bounds__(256) void edge_kernel(const int* __restrict__ src,
                                                   const int* __restrict__ dst,
                                                   const ushort* __restrict__ uvb,
                                                   const float* __restrict__ wc2,
                                                   const float* __restrict__ bc2,
                                                   float* __restrict__ out) {
    int e = blockIdx.x * blockDim.x + threadIdx.x;
    if (e >= N_EDGES) return;
    const uint* ua = (const uint*)(uvb + (size_t)src[e] * 128);
    const uint* va = (const uint*)(uvb + (size_t)dst[e] * 128 + 64);
    float o0 = 0.0f, o1 = 0.0f;
#pragma unroll
    for (int k = 0; k < 32; ++k) {
        uint a = ua[k], b = va[k];
        float h0 = fmaxf(bflo(a) + bflo(b), 0.0f);
        float h1 = fmaxf(bfhi(a) + bfhi(b), 0.0f);
        o0 += wc2[2 * k] * h0 + wc2[2 * k + 1] * h1;
        o1 += wc2[64 + 2 * k] * h0 + wc2[65 + 2 * k] * h1;
    }
    float2 r;
    r.x = o0 + bc2[0];
    r.y = o1 + bc2[1];
    *(float2*)(out + (size_t)e * 2) = r;
}

extern "C" void kernel_launch(void* const* d_in, const int* in_sizes, int n_in,
                              void* d_out, int out_size, void* d_ws, size_t ws_size,
                              hipStream_t stream) {
    const float* x   = (const float*)d_in[0];
    const int*   ei  = (const int*)d_in[1];
    const float* w1l = (const float*)d_in[2];
    const float* b1l = (const float*)d_in[3];
    const float* w1r = (const float*)d_in[4];
    const float* w2l = (const float*)d_in[5];
    const float* b2l = (const float*)d_in[6];
    const float* w2r = (const float*)d_in[7];
    const float* wc1 = (const float*)d_in[8];
    const float* bc1 = (const float*)d_in[9];
    const float* wc2 = (const float*)d_in[10];
    const float* bc2 = (const float*)d_in[11];
    float* out = (float*)d_out;

    const int* srcp = ei;             // edge_index[0]
    const int* dstp = ei + N_EDGES;   // edge_index[1]

    // workspace layout (f32 slots); xb/y2b share, mean1/uvb share (liveness disjoint)
    float*  ws    = (float*)d_ws;
    ushort* xb    = (ushort*)ws;                 // [0, 3.2M)  6.4M bf16
    ushort* y2b   = (ushort*)ws;                 //            (alias, after agg1)
    float*  mean1 = ws + 3200000;                // [3.2M, 9.6M)
    ushort* uvb   = (ushort*)(ws + 3200000);     //            (alias, after layer1)
    float*  h1    = ws + 9600000;                // [9.6M, 22.4M)
    float*  mean2 = ws + 22400000;               // [22.4M, 28.8M)
    int*    ib    = (int*)(ws + 28800000);
    int* cnt       = ib;                 // 100000
    int* row_start = ib + 100000;        // 100000
    int* cursor    = ib + 200000;        // 100000
    int* partial   = ib + 300000;        // 512
    int* nbr       = ib + 300512;        // 1600000

    hipMemsetAsync(cnt, 0, (size_t)N_NODES * 4, stream);

    convert_kernel<<<12500, 256, 0, stream>>>(x, xb);
    degree_kernel<<<(N_EDGES + 255) / 256, 256, 0, stream>>>(dstp, cnt);
    scan_block_sums<<<NBLK_SCAN, 256, 0, stream>>>(cnt, partial);
    scan_top<<<1, 512, 0, stream>>>(partial);
    scan_final<<<NBLK_SCAN, 256, 0, stream>>>(cnt, partial, row_start, cursor);
    fill_sliced<<<1024, 256, 0, stream>>>(srcp, dstp, cursor, nbr);

    const int NAB = (N_NODES + 3) / 4;
    const int NB  = (N_NODES + 63) / 64;

    agg_mean64_bf16<<<NAB, 256, 0, stream>>>(row_start, cnt, nbr, xb, mean1);
    layer1_fused<<<NB, 256, 0, stream>>>(x, mean1, w1r, w1l, b1l, w2l, h1, y2b);
    agg_mean64_bf16<<<NAB, 256, 0, stream>>>(row_start, cnt, nbr, y2b, mean2);
    layer2_uv_fused<<<NB, 256, 0, stream>>>(h1, mean2, w2r, b2l, wc1, bc1, uvb);
    edge_kernel<<<(N_EDGES + 255) / 256, 256, 0, stream>>>(srcp, dstp, uvb, wc2, bc2, out);
}

// Round 6
// 446.735 us; speedup vs baseline: 6.6764x; 1.2503x over previous
//
#include <hip/hip_runtime.h>

#define N_NODES 100000
#define N_EDGES 1600000
#define NBLK_SCAN 391  // ceil(N_NODES/256)
#define SLICE_NODES 12500   // N_NODES/8
#define FILL_CHUNK 12500    // N_EDGES/128

typedef unsigned int uint;
typedef unsigned short ushort;
typedef __attribute__((ext_vector_type(8))) short bf16x8;
typedef __attribute__((ext_vector_type(4))) float f32x4;

__device__ inline float bflo(uint u) { union { uint i; float f; } c; c.i = u << 16; return c.f; }
__device__ inline float bfhi(uint u) { union { uint i; float f; } c; c.i = u & 0xffff0000u; return c.f; }
__device__ inline float bf2f(ushort h) { union { uint i; float f; } c; c.i = (uint)h << 16; return c.f; }
__device__ inline ushort f2bf(float f) {
    union { float f; uint u; } c; c.f = f;
    uint r = (c.u + 0x7fffu + ((c.u >> 16) & 1u)) >> 16;
    return (ushort)r;
}

// weight table offsets (in ushorts) inside Whi/Wlo
#define W1_OFF   0        // [128][128]  [w1r | w1l] concat along k
#define W2L_OFF  16384    // [64][128]
#define W2R_OFF  24576    // [64][128]
#define WC1_OFF  32768    // [128][64]   o<64: wc1[o][0:64] (u); o>=64: wc1[o-64][64:128] (v)
#define W_TOTAL  40960

// ---------------- weight split prep: W ~= Whi + Wlo (bf16 each) ----------------
__global__ __launch_bounds__(256) void prep_weights(const float* __restrict__ w1r,
                                                    const float* __restrict__ w1l,
                                                    const float* __restrict__ w2l,
                                                    const float* __restrict__ w2r,
                                                    const float* __restrict__ wc1,
                                                    ushort* __restrict__ Whi,
                                                    ushort* __restrict__ Wlo) {
    int idx = blockIdx.x * 256 + threadIdx.x;
    if (idx >= W_TOTAL) return;
    float v;
    if (idx < W2L_OFF) {
        int o = idx >> 7, k = idx & 127;
        v = (k < 64) ? w1r[o * 64 + k] : w1l[o * 64 + (k - 64)];
    } else if (idx < W2R_OFF) {
        int t2 = idx - W2L_OFF; int o = t2 >> 7, k = t2 & 127;
        v = w2l[o * 128 + k];
    } else if (idx < WC1_OFF) {
        int t2 = idx - W2R_OFF; int o = t2 >> 7, k = t2 & 127;
        v = w2r[o * 128 + k];
    } else {
        int t2 = idx - WC1_OFF; int o = t2 >> 6, k = t2 & 63;
        v = wc1[(o & 63) * 128 + ((o >> 6) << 6) + k];
    }
    ushort hi = f2bf(v);
    ushort lo = f2bf(v - bf2f(hi));
    Whi[idx] = hi; Wlo[idx] = lo;
}

// ---------------- f32 -> bf16 convert (x) ----------------
__global__ __launch_bounds__(256) void convert_kernel(const float* __restrict__ x,
                                                      ushort* __restrict__ xb) {
    int i = blockIdx.x * 256 + threadIdx.x;
    if (i < N_NODES * 32) {
        float2 v = ((const float2*)x)[i];
        uint o = (uint)f2bf(v.x) | ((uint)f2bf(v.y) << 16);
        ((uint*)xb)[i] = o;
    }
}

// ---------------- degree count ----------------
__global__ __launch_bounds__(256) void degree_kernel(const int* __restrict__ dst,
                                                     int* __restrict__ cnt) {
    int e = blockIdx.x * blockDim.x + threadIdx.x;
    if (e < N_EDGES) atomicAdd(&cnt[dst[e]], 1);
}

// ---------------- scan step 1 ----------------
__global__ __launch_bounds__(256) void scan_block_sums(const int* __restrict__ cnt,
                                                       int* __restrict__ partial) {
    __shared__ int red[4];
    int i = blockIdx.x * 256 + threadIdx.x;
    int v = (i < N_NODES) ? cnt[i] : 0;
#pragma unroll
    for (int off = 32; off; off >>= 1) v += __shfl_down(v, off, 64);
    if ((threadIdx.x & 63) == 0) red[threadIdx.x >> 6] = v;
    __syncthreads();
    if (threadIdx.x == 0) partial[blockIdx.x] = red[0] + red[1] + red[2] + red[3];
}

// ---------------- scan step 2 ----------------
__global__ __launch_bounds__(512) void scan_top(int* __restrict__ partial) {
    __shared__ int s[512];
    int t = threadIdx.x;
    int orig = (t < NBLK_SCAN) ? partial[t] : 0;
    s[t] = orig;
    __syncthreads();
#pragma unroll
    for (int off = 1; off < 512; off <<= 1) {
        int v = (t >= off) ? s[t - off] : 0;
        __syncthreads();
        s[t] += v;
        __syncthreads();
    }
    if (t < NBLK_SCAN) partial[t] = s[t] - orig;
}

// ---------------- scan step 3 ----------------
__global__ __launch_bounds__(256) void scan_final(const int* __restrict__ cnt,
                                                  const int* __restrict__ partial,
                                                  int* __restrict__ row_start,
                                                  int* __restrict__ cursor) {
    __shared__ int s[256];
    int i = blockIdx.x * 256 + threadIdx.x;
    int t = threadIdx.x;
    int orig = (i < N_NODES) ? cnt[i] : 0;
    s[t] = orig;
    __syncthreads();
#pragma unroll
    for (int off = 1; off < 256; off <<= 1) {
        int v = (t >= off) ? s[t - off] : 0;
        __syncthreads();
        s[t] += v;
        __syncthreads();
    }
    if (i < N_NODES) {
        int rs = partial[blockIdx.x] + s[t] - orig;
        row_start[i] = rs;
        cursor[i] = rs;
    }
}

// ---------------- CSR fill, XCD-sliced ----------------
__global__ __launch_bounds__(256) void fill_sliced(const int* __restrict__ src,
                                                   const int* __restrict__ dst,
                                                   int* __restrict__ cursor,
                                                   int* __restrict__ nbr) {
    int slice = blockIdx.x & 7;
    int chunk = blockIdx.x >> 3;
    int lo = slice * SLICE_NODES;
    int hi = lo + SLICE_NODES;
    int ebase = chunk * FILL_CHUNK;
#pragma unroll 1
    for (int e = ebase + threadIdx.x; e < ebase + FILL_CHUNK; e += 256) {
        int d = dst[e];
        if (d >= lo && d < hi) {
            int pos = atomicAdd(&cursor[d], 1);
            nbr[pos] = src[e];
        }
    }
}

// ---------------- gather-mean, bf16 features, D=64 ----------------
__global__ __launch_bounds__(256) void agg_mean64_bf16(const int* __restrict__ row_start,
                                                       const int* __restrict__ cnt,
                                                       const int* __restrict__ nbr,
                                                       const ushort* __restrict__ feat,
                                                       float* __restrict__ outmean) {
    int node = blockIdx.x * 4 + (threadIdx.x >> 6);
    if (node >= N_NODES) return;
    int lane = threadIdx.x & 63;
    int half = lane >> 5;
    int f2   = lane & 31;
    int s = row_start[node];
    int d = cnt[node];
    float ax = 0.0f, ay = 0.0f;
    int p = 0;
    for (; p + 4 <= d; p += 4) {
        int n0 = nbr[s + p + half];
        int n1 = nbr[s + p + 2 + half];
        uint w0 = *(const uint*)(feat + (size_t)n0 * 64 + f2 * 2);
        uint w1 = *(const uint*)(feat + (size_t)n1 * 64 + f2 * 2);
        ax += bflo(w0) + bflo(w1);
        ay += bfhi(w0) + bfhi(w1);
    }
    for (; p + 2 <= d; p += 2) {
        int n0 = nbr[s + p + half];
        uint w0 = *(const uint*)(feat + (size_t)n0 * 64 + f2 * 2);
        ax += bflo(w0);
        ay += bfhi(w0);
    }
    if (p < d && half == 0) {
        int n0 = nbr[s + p];
        uint w0 = *(const uint*)(feat + (size_t)n0 * 64 + f2 * 2);
        ax += bflo(w0);
        ay += bfhi(w0);
    }
    ax += __shfl_xor(ax, 32, 64);
    ay += __shfl_xor(ay, 32, 64);
    if (half == 0) {
        float inv = 1.0f / fmaxf((float)d, 1.0f);
        float2 o; o.x = ax * inv; o.y = ay * inv;
        *(float2*)&outmean[(size_t)node * 64 + f2 * 2] = o;
    }
}

// ======== MFMA transform kernels (bf16 hi/lo split, 3-product compensation) ========
// Fragment layout (v_mfma_f32_16x16x32_bf16): A[m][k]: m=lane&15, k=8*(lane>>4)+i.
// B[k][n]: n=lane&15, k=8*(lane>>4)+i  -> B frag = W[n][k] natural row-major 16B load.
// C/D: col(n)=lane&15, row(m)=(lane>>4)*4+reg   [verified m89]

#define MFMA __builtin_amdgcn_mfma_f32_16x16x32_bf16

// G1+G2: h1 = relu([x|mean1]@W1^T + b1l) (K=128,N=128); y2 = h1@w2l^T (K=128,N=64)
// 64 nodes/block, 4 waves; wave owns 32 outputs (G1) / 16 outputs (G2), all 64 nodes.
__global__ __launch_bounds__(256) void g1g2_kernel(const float* __restrict__ x,
                                                   const float* __restrict__ mean1,
                                                   const ushort* __restrict__ Whi,
                                                   const ushort* __restrict__ Wlo,
                                                   const float* __restrict__ b1l,
                                                   ushort* __restrict__ h1hi,
                                                   ushort* __restrict__ h1lo,
                                                   ushort* __restrict__ y2b) {
    __shared__ ushort Ah[64 * 136];   // A hi, stride 136 (272B = 17*16, aligned+2-way banks)
    __shared__ ushort Al[64 * 136];   // A lo ; reused as h1 hi/lo after G1 MFMA
    const int t = threadIdx.x;
    const int l = t & 63;
    const int wv = t >> 6;
    const int base = blockIdx.x * 64;
    const int lr = l & 15;            // fragment row/col
    const int lk = (l >> 4) * 8;      // fragment k-offset

    // stage [x | mean1] split hi/lo into LDS
    for (int idx = t; idx < 2048; idx += 256) {
        int halfsel = idx >> 10;
        int id2 = idx & 1023;
        int n = id2 >> 4;
        int k0 = (id2 & 15) * 4;
        int gn = base + n;
        float4 v = make_float4(0.f, 0.f, 0.f, 0.f);
        if (gn < N_NODES) v = *(const float4*)&(halfsel ? mean1 : x)[(size_t)gn * 64 + k0];
        ushort h0 = f2bf(v.x), h1_ = f2bf(v.y), h2_ = f2bf(v.z), h3 = f2bf(v.w);
        ushort l0 = f2bf(v.x - bf2f(h0)), l1 = f2bf(v.y - bf2f(h1_));
        ushort l2 = f2bf(v.z - bf2f(h2_)), l3 = f2bf(v.w - bf2f(h3));
        int col = halfsel * 64 + k0;
        uint2 ph; ph.x = (uint)h0 | ((uint)h1_ << 16); ph.y = (uint)h2_ | ((uint)h3 << 16);
        uint2 pl; pl.x = (uint)l0 | ((uint)l1 << 16); pl.y = (uint)l2 | ((uint)l3 << 16);
        *(uint2*)&Ah[n * 136 + col] = ph;
        *(uint2*)&Al[n * 136 + col] = pl;
    }
    __syncthreads();

    // G1 MFMA: acc[m4][n2]
    f32x4 acc[4][2];
#pragma unroll
    for (int m4 = 0; m4 < 4; ++m4)
#pragma unroll
        for (int n2 = 0; n2 < 2; ++n2) acc[m4][n2] = (f32x4){0.f, 0.f, 0.f, 0.f};

#pragma unroll
    for (int ks = 0; ks < 4; ++ks) {
        bf16x8 ah[4], al[4];
        int aoff = lr * 136 + ks * 32 + lk;
#pragma unroll
        for (int m4 = 0; m4 < 4; ++m4) {
            ah[m4] = *(const bf16x8*)&Ah[m4 * 2176 + aoff];
            al[m4] = *(const bf16x8*)&Al[m4 * 2176 + aoff];
        }
#pragma unroll
        for (int n2 = 0; n2 < 2; ++n2) {
            int o = wv * 32 + n2 * 16 + lr;
            int woff = W1_OFF + o * 128 + ks * 32 + lk;
            bf16x8 bh = *(const bf16x8*)&Whi[woff];
            bf16x8 bl = *(const bf16x8*)&Wlo[woff];
#pragma unroll
            for (int m4 = 0; m4 < 4; ++m4) {
                acc[m4][n2] = MFMA(al[m4], bh, acc[m4][n2], 0, 0, 0);
                acc[m4][n2] = MFMA(ah[m4], bl, acc[m4][n2], 0, 0, 0);
                acc[m4][n2] = MFMA(ah[m4], bh, acc[m4][n2], 0, 0, 0);
            }
        }
    }
    __syncthreads();  // A dead; alias h1 onto it
    ushort* H1h = Ah;
    ushort* H1l = Al;

    // G1 epilogue: bias + relu, split -> LDS h1
#pragma unroll
    for (int n2 = 0; n2 < 2; ++n2) {
        int o = wv * 32 + n2 * 16 + lr;
        float bb = b1l[o];
#pragma unroll
        for (int m4 = 0; m4 < 4; ++m4) {
#pragma unroll
            for (int r = 0; r < 4; ++r) {
                int nl = m4 * 16 + (l >> 4) * 4 + r;
                float val = fmaxf(acc[m4][n2][r] + bb, 0.f);
                ushort hi = f2bf(val);
                ushort lo = f2bf(val - bf2f(hi));
                H1h[nl * 136 + o] = hi;
                H1l[nl * 136 + o] = lo;
            }
        }
    }
    __syncthreads();

    // coalesced h1 -> global (split bf16)
    for (int idx = t; idx < 2048; idx += 256) {
        int n = idx >> 5;
        int c4 = (idx & 31) * 4;
        int gn = base + n;
        if (gn < N_NODES) {
            *(uint2*)&h1hi[(size_t)gn * 128 + c4] = *(uint2*)&H1h[n * 136 + c4];
            *(uint2*)&h1lo[(size_t)gn * 128 + c4] = *(uint2*)&H1l[n * 136 + c4];
        }
    }

    // G2: y2 = h1 @ w2l^T  (N=64, wave owns 16 outputs)
    f32x4 acc2[4];
#pragma unroll
    for (int m4 = 0; m4 < 4; ++m4) acc2[m4] = (f32x4){0.f, 0.f, 0.f, 0.f};
#pragma unroll
    for (int ks = 0; ks < 4; ++ks) {
        int aoff = lr * 136 + ks * 32 + lk;
        int o2 = wv * 16 + lr;
        int woff = W2L_OFF + o2 * 128 + ks * 32 + lk;
        bf16x8 bh = *(const bf16x8*)&Whi[woff];
        bf16x8 bl = *(const bf16x8*)&Wlo[woff];
#pragma unroll
        for (int m4 = 0; m4 < 4; ++m4) {
            bf16x8 ah = *(const bf16x8*)&H1h[m4 * 2176 + aoff];
            bf16x8 al = *(const bf16x8*)&H1l[m4 * 2176 + aoff];
            acc2[m4] = MFMA(al, bh, acc2[m4], 0, 0, 0);
            acc2[m4] = MFMA(ah, bl, acc2[m4], 0, 0, 0);
            acc2[m4] = MFMA(ah, bh, acc2[m4], 0, 0, 0);
        }
    }
#pragma unroll
    for (int m4 = 0; m4 < 4; ++m4) {
#pragma unroll
        for (int r = 0; r < 4; ++r) {
            int nl = m4 * 16 + (l >> 4) * 4 + r;
            int gn = base + nl;
            if (gn < N_NODES) y2b[(size_t)gn * 64 + wv * 16 + lr] = f2bf(acc2[m4][r]);
        }
    }
}

// G3+G4: h2 = relu(h1@w2r^T + mean2 + b2l) (K=128,N=64); uv = h2@wc1'^T + [bc1|0] (K=64,N=128)
__global__ __launch_bounds__(256) void g3g4_kernel(const ushort* __restrict__ h1hi,
                                                   const ushort* __restrict__ h1lo,
                                                   const float* __restrict__ mean2,
                                                   const ushort* __restrict__ Whi,
                                                   const ushort* __restrict__ Wlo,
                                                   const float* __restrict__ b2l,
                                                   const float* __restrict__ bc1,
                                                   ushort* __restrict__ uvb) {
    __shared__ ushort H1h[64 * 136];   // reused as h2 hi (stride 72) after G3
    __shared__ ushort H1l[64 * 136];
    __shared__ float  M2[64 * 68];
    const int t = threadIdx.x;
    const int l = t & 63;
    const int wv = t >> 6;
    const int base = blockIdx.x * 64;
    const int lr = l & 15;
    const int lk = (l >> 4) * 8;

    // stage h1 (already split bf16) and mean2
    for (int idx = t; idx < 2048; idx += 256) {
        int n = idx >> 5;
        int c4 = (idx & 31) * 4;
        int gn = base + n;
        uint2 vh = make_uint2(0u, 0u), vl = make_uint2(0u, 0u);
        if (gn < N_NODES) {
            vh = *(const uint2*)&h1hi[(size_t)gn * 128 + c4];
            vl = *(const uint2*)&h1lo[(size_t)gn * 128 + c4];
        }
        *(uint2*)&H1h[n * 136 + c4] = vh;
        *(uint2*)&H1l[n * 136 + c4] = vl;
    }
    for (int idx = t; idx < 1024; idx += 256) {
        int n = idx >> 4;
        int k0 = (idx & 15) * 4;
        int gn = base + n;
        float4 v = make_float4(0.f, 0.f, 0.f, 0.f);
        if (gn < N_NODES) v = *(const float4*)&mean2[(size_t)gn * 64 + k0];
        *(float4*)&M2[n * 68 + k0] = v;
    }
    __syncthreads();

    // G3 MFMA (N=64, wave owns 16 outputs)
    f32x4 acc[4];
#pragma unroll
    for (int m4 = 0; m4 < 4; ++m4) acc[m4] = (f32x4){0.f, 0.f, 0.f, 0.f};
#pragma unroll
    for (int ks = 0; ks < 4; ++ks) {
        int aoff = lr * 136 + ks * 32 + lk;
        int o2 = wv * 16 + lr;
        int woff = W2R_OFF + o2 * 128 + ks * 32 + lk;
        bf16x8 bh = *(const bf16x8*)&Whi[woff];
        bf16x8 bl = *(const bf16x8*)&Wlo[woff];
#pragma unroll
        for (int m4 = 0; m4 < 4; ++m4) {
            bf16x8 ah = *(const bf16x8*)&H1h[m4 * 2176 + aoff];
            bf16x8 al = *(const bf16x8*)&H1l[m4 * 2176 + aoff];
            acc[m4] = MFMA(al, bh, acc[m4], 0, 0, 0);
            acc[m4] = MFMA(ah, bl, acc[m4], 0, 0, 0);
            acc[m4] = MFMA(ah, bh, acc[m4], 0, 0, 0);
        }
    }
    __syncthreads();  // all reads of H1 done; alias h2 (stride 72)
    ushort* H2h = H1h;
    ushort* H2l = H1l;

    // G3 epilogue: + mean2 + bias, relu, split -> LDS h2
    {
        int o2 = wv * 16 + lr;
        float bb = b2l[o2];
#pragma unroll
        for (int m4 = 0; m4 < 4; ++m4) {
#pragma unroll
            for (int r = 0; r < 4; ++r) {
                int nl = m4 * 16 + (l >> 4) * 4 + r;
                float val = fmaxf(acc[m4][r] + M2[nl * 68 + o2] + bb, 0.f);
                ushort hi = f2bf(val);
                ushort lo = f2bf(val - bf2f(hi));
                H2h[nl * 72 + o2] = hi;
                H2l[nl * 72 + o2] = lo;
            }
        }
    }
    __syncthreads();

    // G4: uv = h2 @ wc1'^T  (K=64, N=128, wave owns 32 outputs)
    f32x4 acc4[4][2];
#pragma unroll
    for (int m4 = 0; m4 < 4; ++m4)
#pragma unroll
        for (int n2 = 0; n2 < 2; ++n2) acc4[m4][n2] = (f32x4){0.f, 0.f, 0.f, 0.f};
#pragma unroll
    for (int ks = 0; ks < 2; ++ks) {
        bf16x8 ah[4], al[4];
        int aoff = lr * 72 + ks * 32 + lk;
#pragma unroll
        for (int m4 = 0; m4 < 4; ++m4) {
            ah[m4] = *(const bf16x8*)&H2h[m4 * 1152 + aoff];
            al[m4] = *(const bf16x8*)&H2l[m4 * 1152 + aoff];
        }
#pragma unroll
        for (int n2 = 0; n2 < 2; ++n2) {
            int o = wv * 32 + n2 * 16 + lr;
            int woff = WC1_OFF + o * 64 + ks * 32 + lk;
            bf16x8 bh = *(const bf16x8*)&Whi[woff];
            bf16x8 bl = *(const bf16x8*)&Wlo[woff];
#pragma unroll
            for (int m4 = 0; m4 < 4; ++m4) {
                acc4[m4][n2] = MFMA(al[m4], bh, acc4[m4][n2], 0, 0, 0);
                acc4[m4][n2] = MFMA(ah[m4], bl, acc4[m4][n2], 0, 0, 0);
                acc4[m4][n2] = MFMA(ah[m4], bh, acc4[m4][n2], 0, 0, 0);
            }
        }
    }
    // G4 epilogue -> uvb bf16
#pragma unroll
    for (int n2 = 0; n2 < 2; ++n2) {
        int o = wv * 32 + n2 * 16 + lr;
        float bb = (o < 64) ? bc1[o] : 0.0f;
#pragma unroll
        for (int m4 = 0; m4 < 4; ++m4) {
#pragma unroll
            for (int r = 0; r < 4; ++r) {
                int nl = m4 * 16 + (l >> 4) * 4 + r;
                int gn = base + nl;
                if (gn < N_NODES) uvb[(size_t)gn * 128 + o] = f2bf(acc4[m4][n2][r] + bb);
            }
        }
    }
}

// ---------------- edge kernel: out = wc2 @ relu(u[src]+v[dst]) + bc2, bf16 uv ---------
__global__ __launch_bounds__(256) void edge_kernel(const int* __restrict__ src,
                                                   const int* __restrict__ dst,
                                                   const ushort* __restrict__ uvb,
                                                   const float* __restrict__ wc2,
                                                   const float* __restrict__ bc2,
                                                   float* __restrict__ out) {
    int e = blockIdx.x * blockDim.x + threadIdx.x;
    if (e >= N_EDGES) return;
    const uint* ua = (const uint*)(uvb + (size_t)src[e] * 128);
    const uint* va = (const uint*)(uvb + (size_t)dst[e] * 128 + 64);
    float o0 = 0.0f, o1 = 0.0f;
#pragma unroll
    for (int k = 0; k < 32; ++k) {
        uint a = ua[k], b = va[k];
        float h0 = fmaxf(bflo(a) + bflo(b), 0.0f);
        float h1 = fmaxf(bfhi(a) + bfhi(b), 0.0f);
        o0 += wc2[2 * k] * h0 + wc2[2 * k + 1] * h1;
        o1 += wc2[64 + 2 * k] * h0 + wc2[65 + 2 * k] * h1;
    }
    float2 r;
    r.x = o0 + bc2[0];
    r.y = o1 + bc2[1];
    *(float2*)(out + (size_t)e * 2) = r;
}

extern "C" void kernel_launch(void* const* d_in, const int* in_sizes, int n_in,
                              void* d_out, int out_size, void* d_ws, size_t ws_size,
                              hipStream_t stream) {
    const float* x   = (const float*)d_in[0];
    const int*   ei  = (const int*)d_in[1];
    const float* w1l = (const float*)d_in[2];
    const float* b1l = (const float*)d_in[3];
    const float* w1r = (const float*)d_in[4];
    const float* w2l = (const float*)d_in[5];
    const float* b2l = (const float*)d_in[6];
    const float* w2r = (const float*)d_in[7];
    const float* wc1 = (const float*)d_in[8];
    const float* bc1 = (const float*)d_in[9];
    const float* wc2 = (const float*)d_in[10];
    const float* bc2 = (const float*)d_in[11];
    float* out = (float*)d_out;

    const int* srcp = ei;
    const int* dstp = ei + N_EDGES;

    // workspace layout (f32 slots)
    float*  ws    = (float*)d_ws;
    ushort* xb    = (ushort*)ws;                 // [0, 3.2M)   bf16 x (alias y2b)
    ushort* y2b   = (ushort*)ws;
    float*  mean1 = ws + 3200000;                // [3.2M, 9.6M) f32 (alias uvb)
    ushort* uvb   = (ushort*)(ws + 3200000);
    ushort* h1hi  = (ushort*)(ws + 9600000);     // [9.6M, 16M)  bf16
    ushort* h1lo  = (ushort*)(ws + 16000000);    // [16M, 22.4M) bf16
    float*  mean2 = ws + 22400000;               // [22.4M, 28.8M)
    int*    ib    = (int*)(ws + 28800000);
    int* cnt       = ib;                 // 100000
    int* row_start = ib + 100000;        // 100000
    int* cursor    = ib + 200000;        // 100000
    int* partial   = ib + 300000;        // 512
    int* nbr       = ib + 300512;        // 1600000
    ushort* Whi = (ushort*)(ws + 30800000);      // 40960 ushorts
    ushort* Wlo = (ushort*)(ws + 30900000);

    hipMemsetAsync(cnt, 0, (size_t)N_NODES * 4, stream);

    prep_weights<<<(W_TOTAL + 255) / 256, 256, 0, stream>>>(w1r, w1l, w2l, w2r, wc1, Whi, Wlo);
    convert_kernel<<<12500, 256, 0, stream>>>(x, xb);
    degree_kernel<<<(N_EDGES + 255) / 256, 256, 0, stream>>>(dstp, cnt);
    scan_block_sums<<<NBLK_SCAN, 256, 0, stream>>>(cnt, partial);
    scan_top<<<1, 512, 0, stream>>>(partial);
    scan_final<<<NBLK_SCAN, 256, 0, stream>>>(cnt, partial, row_start, cursor);
    fill_sliced<<<1024, 256, 0, stream>>>(srcp, dstp, cursor, nbr);

    const int NAB = (N_NODES + 3) / 4;
    const int NB  = (N_NODES + 63) / 64;

    agg_mean64_bf16<<<NAB, 256, 0, stream>>>(row_start, cnt, nbr, xb, mean1);
    g1g2_kernel<<<NB, 256, 0, stream>>>(x, mean1, Whi, Wlo, b1l, h1hi, h1lo, y2b);
    agg_mean64_bf16<<<NAB, 256, 0, stream>>>(row_start, cnt, nbr, y2b, mean2);
    g3g4_kernel<<<NB, 256, 0, stream>>>(h1hi, h1lo, mean2, Whi, Wlo, b2l, bc1, uvb);
    edge_kernel<<<(N_EDGES + 255) / 256, 256, 0, stream>>>(srcp, dstp, uvb, wc2, bc2, out);
}